// Round 1
// baseline (541.987 us; speedup 1.0000x reference)
//
#include <hip/hip_runtime.h>
#include <hip/hip_bf16.h>

#define N_NODES 16384
#define E_EDGES 131072
#define F_IN 6
#define S_DIM 4
#define G_GRAPHS 256
#define H_DIM 30
#define C1 32
#define C2 64
#define C3 32

// ---------------------------------------------------------------------------
// ECC1: per-edge kernel-net (4->30->30->192) fused with x[src] contraction.
// 8 edges per 256-thread block, 32 lanes per edge (lane = output channel c).
// Weights staged in LDS once per block; grid-stride over edge batches.
// ---------------------------------------------------------------------------
__global__ __launch_bounds__(256) void ecc1_edges(
    const float* __restrict__ x, const float* __restrict__ e,
    const int* __restrict__ src, const int* __restrict__ tgt,
    const float* __restrict__ w0, const float* __restrict__ b0,
    const float* __restrict__ w1, const float* __restrict__ b1,
    const float* __restrict__ wk, const float* __restrict__ bk,
    float* __restrict__ agg1)
{
    __shared__ float s_w0[120], s_b0[32], s_w1[900], s_b1[32];
    __shared__ float s_wk[5760], s_bk[192];
    __shared__ float s_h0[8][33], s_h1[8][33], s_xs[8][8];

    const int t = threadIdx.x;
    for (int i = t; i < 120; i += 256) s_w0[i] = w0[i];
    for (int i = t; i < 900; i += 256) s_w1[i] = w1[i];
    for (int i = t; i < 5760; i += 256) s_wk[i] = wk[i];
    for (int i = t; i < 192; i += 256) s_bk[i] = bk[i];
    if (t < 30) { s_b0[t] = b0[t]; s_b1[t] = b1[t]; }
    __syncthreads();

    const int eg = t >> 5;      // 0..7 edge slot
    const int lane = t & 31;    // output channel

    for (int base = blockIdx.x * 8; base < E_EDGES; base += gridDim.x * 8) {
        const int eid = base + eg;   // E is an exact multiple of grid*8
        // ---- h0 = relu(e @ w0 + b0) ----
        const float4 ev = *(const float4*)(e + eid * 4);
        if (lane < 30) {
            float v = ev.x * s_w0[lane] + ev.y * s_w0[30 + lane]
                    + ev.z * s_w0[60 + lane] + ev.w * s_w0[90 + lane] + s_b0[lane];
            s_h0[eg][lane] = fmaxf(v, 0.f);
        }
        if (lane < 6) s_xs[eg][lane] = x[src[eid] * F_IN + lane];
        __syncthreads();
        // ---- h1 = relu(h0 @ w1 + b1) ----
        if (lane < 30) {
            float v = s_b1[lane];
            #pragma unroll
            for (int k = 0; k < 30; ++k) v += s_h0[eg][k] * s_w1[k * 30 + lane];
            s_h1[eg][lane] = fmaxf(v, 0.f);
        }
        __syncthreads();
        // ---- msg[c] = sum_h h1[h] * (sum_f x_f * wk[h, f*32+c]) + x·bk[:,c] ----
        const float x0 = s_xs[eg][0], x1v = s_xs[eg][1], x2v = s_xs[eg][2];
        const float x3v = s_xs[eg][3], x4v = s_xs[eg][4], x5v = s_xs[eg][5];
        float acc = x0 * s_bk[lane] + x1v * s_bk[32 + lane] + x2v * s_bk[64 + lane]
                  + x3v * s_bk[96 + lane] + x4v * s_bk[128 + lane] + x5v * s_bk[160 + lane];
        #pragma unroll 6
        for (int h = 0; h < 30; ++h) {
            const float* wr = s_wk + h * 192 + lane;
            float u = x0 * wr[0] + x1v * wr[32] + x2v * wr[64]
                    + x3v * wr[96] + x4v * wr[128] + x5v * wr[160];
            acc += s_h1[eg][h] * u;
        }
        atomicAdd(&agg1[tgt[eid] * C1 + lane], acc);
        __syncthreads();   // protect s_h0/s_xs before next batch overwrites
    }
}

// x1 = relu(agg1 + x @ root + bias), in-place on agg buffer. N*C1 threads.
__global__ __launch_bounds__(256) void node_update1(
    const float* __restrict__ x, const float* __restrict__ root,
    const float* __restrict__ bias, float* __restrict__ buf)
{
    const int t = blockIdx.x * 256 + threadIdx.x;
    const int n = t >> 5, c = t & 31;
    const float* xr = x + n * F_IN;
    float v = buf[t] + bias[c];
    #pragma unroll
    for (int f = 0; f < F_IN; ++f) v += xr[f] * root[f * C1 + c];
    buf[t] = fmaxf(v, 0.f);
}

// ---------------------------------------------------------------------------
// ECC2: the big one. msg = (h1 ⊗ x1[src]) @ Wk' as an edge-tile GEMM.
// 64 edges per 256-thread block; thread tile 4 edges x 4 c2; Wk read from
// global (245 KB, L2-resident, 16x L1 broadcast reuse inside block).
// ---------------------------------------------------------------------------
__global__ __launch_bounds__(256) void ecc2_edges(
    const float* __restrict__ x1, const float* __restrict__ e,
    const int* __restrict__ src, const int* __restrict__ tgt,
    const float* __restrict__ w0, const float* __restrict__ b0,
    const float* __restrict__ w1, const float* __restrict__ b1,
    const float* __restrict__ wk, const float* __restrict__ bk,
    float* __restrict__ agg2)
{
    __shared__ float s_w0[120], s_b0[32], s_w1[900], s_b1[32];
    __shared__ float s_h1[64][33];
    __shared__ float s_xs[64][33];

    const int t = threadIdx.x;
    for (int i = t; i < 120; i += 256) s_w0[i] = w0[i];
    for (int i = t; i < 900; i += 256) s_w1[i] = w1[i];
    if (t < 30) { s_b0[t] = b0[t]; s_b1[t] = b1[t]; }

    const int tile = blockIdx.x * 64;
    const int e_loc = t >> 2;   // 0..63
    const int p = t & 3;        // 0..3, handles h/c1 slice [p*8, p*8+8)
    const int eid = tile + e_loc;
    __syncthreads();

    // ---- phase A: edge MLP h0 -> h1, stage x1[src] ----
    const float4 ev = *(const float4*)(e + eid * 4);
    #pragma unroll
    for (int i = 0; i < 8; ++i) {
        const int j = p * 8 + i;
        if (j < 30) {
            float v = ev.x * s_w0[j] + ev.y * s_w0[30 + j]
                    + ev.z * s_w0[60 + j] + ev.w * s_w0[90 + j] + s_b0[j];
            s_h1[e_loc][j] = fmaxf(v, 0.f);
        }
    }
    const int sb = src[eid] * C1;
    #pragma unroll
    for (int i = 0; i < 8; ++i) s_xs[e_loc][p * 8 + i] = x1[sb + p * 8 + i];
    __syncthreads();
    float hv[8];
    #pragma unroll
    for (int i = 0; i < 8; ++i) {
        const int j = p * 8 + i;
        float v = 0.f;
        if (j < 30) {
            v = s_b1[j];
            #pragma unroll
            for (int k = 0; k < 30; ++k) v += s_h1[e_loc][k] * s_w1[k * 30 + j];
            v = fmaxf(v, 0.f);
        }
        hv[i] = v;
    }
    __syncthreads();
    #pragma unroll
    for (int i = 0; i < 8; ++i) {
        const int j = p * 8 + i;
        if (j < 30) s_h1[e_loc][j] = hv[i];
    }
    __syncthreads();

    // ---- phase B: GEMM.  thread = (eg 0..15, cg 0..15) -> edges eg*4+{0..3},
    //      channels c2 = cg*4+{0..3} ----
    const int eg = t >> 4;
    const int cg = t & 15;
    const int c2 = cg * 4;

    float acc[4][4];
    #pragma unroll
    for (int i = 0; i < 4; ++i)
        #pragma unroll
        for (int j = 0; j < 4; ++j) acc[i][j] = 0.f;

    // bias contribution: sum_c1 x1[c1] * bk[c1*64 + c2]
    #pragma unroll 8
    for (int c1 = 0; c1 < 32; ++c1) {
        const float4 bkv = *(const float4*)(bk + c1 * 64 + c2);
        #pragma unroll
        for (int i = 0; i < 4; ++i) {
            const float xv = s_xs[eg * 4 + i][c1];
            acc[i][0] += xv * bkv.x; acc[i][1] += xv * bkv.y;
            acc[i][2] += xv * bkv.z; acc[i][3] += xv * bkv.w;
        }
    }

    // main loop: c1 tiled by 8 (register-cache x1 slices across all 30 h)
    #pragma unroll
    for (int blk = 0; blk < 4; ++blk) {
        float xr[4][8];
        #pragma unroll
        for (int i = 0; i < 4; ++i)
            #pragma unroll
            for (int cc = 0; cc < 8; ++cc) xr[i][cc] = s_xs[eg * 4 + i][blk * 8 + cc];

        for (int h = 0; h < 30; ++h) {
            float t4[4][4];
            #pragma unroll
            for (int i = 0; i < 4; ++i)
                #pragma unroll
                for (int j = 0; j < 4; ++j) t4[i][j] = 0.f;
            const float* wrow = wk + h * 2048 + blk * 8 * 64 + c2;
            #pragma unroll
            for (int cc = 0; cc < 8; ++cc) {
                const float4 wv = *(const float4*)(wrow + cc * 64);
                #pragma unroll
                for (int i = 0; i < 4; ++i) {
                    t4[i][0] += xr[i][cc] * wv.x; t4[i][1] += xr[i][cc] * wv.y;
                    t4[i][2] += xr[i][cc] * wv.z; t4[i][3] += xr[i][cc] * wv.w;
                }
            }
            #pragma unroll
            for (int i = 0; i < 4; ++i) {
                const float hval = s_h1[eg * 4 + i][h];
                #pragma unroll
                for (int j = 0; j < 4; ++j) acc[i][j] += hval * t4[i][j];
            }
        }
    }

    // ---- scatter ----
    #pragma unroll
    for (int i = 0; i < 4; ++i) {
        const int tb = tgt[tile + eg * 4 + i] * C2 + c2;
        #pragma unroll
        for (int j = 0; j < 4; ++j) atomicAdd(&agg2[tb + j], acc[i][j]);
    }
}

// x2 = relu(agg2 + x1 @ root2 + bias2), in-place. N*C2 threads.
__global__ __launch_bounds__(256) void node_update2(
    const float* __restrict__ x1, const float* __restrict__ root,
    const float* __restrict__ bias, float* __restrict__ buf)
{
    const int t = blockIdx.x * 256 + threadIdx.x;
    const int n = t >> 6, c = t & 63;
    const float* xr = x1 + n * C1;
    float v = buf[t] + bias[c];
    #pragma unroll 8
    for (int k = 0; k < C1; ++k) v += xr[k] * root[k * C2 + c];
    buf[t] = fmaxf(v, 0.f);
}

// xw = x2 @ gcn_W.  N*C3 threads.
__global__ __launch_bounds__(256) void xw_kernel(
    const float* __restrict__ x2, const float* __restrict__ W,
    float* __restrict__ xw)
{
    const int t = blockIdx.x * 256 + threadIdx.x;
    const int n = t >> 5, c = t & 31;
    const float* xr = x2 + n * C2;
    float v = 0.f;
    #pragma unroll 8
    for (int k = 0; k < C2; ++k) v += xr[k] * W[k * C3 + c];
    xw[t] = v;
}

// weighted scatter over gcn edge list (E+N entries), 32 lanes per edge.
__global__ __launch_bounds__(256) void gcn_scatter(
    const float* __restrict__ xw, const int* __restrict__ gs,
    const int* __restrict__ gt, const float* __restrict__ gw,
    float* __restrict__ agg3)
{
    const int t = blockIdx.x * 256 + threadIdx.x;
    const int i = t >> 5, lane = t & 31;
    const float v = gw[i] * xw[gs[i] * C3 + lane];
    atomicAdd(&agg3[gt[i] * C3 + lane], v);
}

// x3 = relu(agg3 + b); pool into out[seg[n]]. N*C3 threads.
__global__ __launch_bounds__(256) void final_pool(
    const float* __restrict__ agg3, const float* __restrict__ gb,
    const int* __restrict__ seg, float* __restrict__ out)
{
    const int t = blockIdx.x * 256 + threadIdx.x;
    const int n = t >> 5, c = t & 31;
    const float v = fmaxf(agg3[t] + gb[c], 0.f);
    atomicAdd(&out[seg[n] * C3 + c], v);
}

extern "C" void kernel_launch(void* const* d_in, const int* in_sizes, int n_in,
                              void* d_out, int out_size, void* d_ws, size_t ws_size,
                              hipStream_t stream)
{
    const float* x       = (const float*)d_in[0];
    const float* e       = (const float*)d_in[1];
    const int*   src     = (const int*)d_in[2];
    const int*   tgt     = (const int*)d_in[3];
    const int*   seg     = (const int*)d_in[4];
    const int*   gcn_src = (const int*)d_in[5];
    const int*   gcn_tgt = (const int*)d_in[6];
    const float* gcn_w   = (const float*)d_in[7];
    const float* e1_w0   = (const float*)d_in[8];
    const float* e1_b0   = (const float*)d_in[9];
    const float* e1_w1   = (const float*)d_in[10];
    const float* e1_b1   = (const float*)d_in[11];
    const float* e1_wk   = (const float*)d_in[12];
    const float* e1_bk   = (const float*)d_in[13];
    const float* e1_root = (const float*)d_in[14];
    const float* e1_bias = (const float*)d_in[15];
    const float* e2_w0   = (const float*)d_in[16];
    const float* e2_b0   = (const float*)d_in[17];
    const float* e2_w1   = (const float*)d_in[18];
    const float* e2_b1   = (const float*)d_in[19];
    const float* e2_wk   = (const float*)d_in[20];
    const float* e2_bk   = (const float*)d_in[21];
    const float* e2_root = (const float*)d_in[22];
    const float* e2_bias = (const float*)d_in[23];
    const float* gcn_W   = (const float*)d_in[24];
    const float* gcn_b   = (const float*)d_in[25];
    float* out = (float*)d_out;

    float* ws   = (float*)d_ws;
    float* buf1 = ws;                                  // agg1 -> x1   [N, C1]
    float* buf2 = ws + N_NODES * C1;                   // agg2 -> x2   [N, C2]
    float* bxw  = ws + N_NODES * (C1 + C2);            // xw           [N, C3]
    float* buf3 = ws + N_NODES * (C1 + C2 + C3);       // agg3         [N, C3]

    hipMemsetAsync(buf1, 0, (size_t)N_NODES * C1 * sizeof(float), stream);
    hipMemsetAsync(buf2, 0, (size_t)N_NODES * C2 * sizeof(float), stream);
    hipMemsetAsync(buf3, 0, (size_t)N_NODES * C3 * sizeof(float), stream);
    hipMemsetAsync(out, 0, (size_t)out_size * sizeof(float), stream);

    ecc1_edges<<<2048, 256, 0, stream>>>(x, e, src, tgt,
        e1_w0, e1_b0, e1_w1, e1_b1, e1_wk, e1_bk, buf1);
    node_update1<<<(N_NODES * C1) / 256, 256, 0, stream>>>(x, e1_root, e1_bias, buf1);
    ecc2_edges<<<E_EDGES / 64, 256, 0, stream>>>(buf1, e, src, tgt,
        e2_w0, e2_b0, e2_w1, e2_b1, e2_wk, e2_bk, buf2);
    node_update2<<<(N_NODES * C2) / 256, 256, 0, stream>>>(buf1, e2_root, e2_bias, buf2);
    xw_kernel<<<(N_NODES * C3) / 256, 256, 0, stream>>>(buf2, gcn_W, bxw);
    gcn_scatter<<<((E_EDGES + N_NODES) * C3) / 256, 256, 0, stream>>>(
        bxw, gcn_src, gcn_tgt, gcn_w, buf3);
    final_pool<<<(N_NODES * C3) / 256, 256, 0, stream>>>(buf3, gcn_b, seg, out);
}

// Round 2
// 324.937 us; speedup vs baseline: 1.6680x; 1.6680x over previous
//
#include <hip/hip_runtime.h>
#include <hip/hip_bf16.h>

#define N_NODES 16384
#define E_EDGES 131072
#define F_IN 6
#define S_DIM 4
#define G_GRAPHS 256
#define H_DIM 30
#define C1 32
#define C2 64
#define C3 32

typedef __attribute__((ext_vector_type(8))) short bf16x8;
typedef __attribute__((ext_vector_type(4))) float f32x4;

// round-to-nearest-even float -> bf16 bit pattern (no NaN handling needed here)
__device__ __forceinline__ short f2bf(float f) {
    union { float f; unsigned u; } a; a.f = f;
    unsigned r = a.u + 0x7FFFu + ((a.u >> 16) & 1u);
    return (short)(r >> 16);
}

// ---------------------------------------------------------------------------
// ECC1: per-edge kernel-net (4->30->30->192) fused with x[src] contraction.
// 8 edges per 256-thread block, 32 lanes per edge (lane = output channel c).
// ---------------------------------------------------------------------------
__global__ __launch_bounds__(256) void ecc1_edges(
    const float* __restrict__ x, const float* __restrict__ e,
    const int* __restrict__ src, const int* __restrict__ tgt,
    const float* __restrict__ w0, const float* __restrict__ b0,
    const float* __restrict__ w1, const float* __restrict__ b1,
    const float* __restrict__ wk, const float* __restrict__ bk,
    float* __restrict__ agg1)
{
    __shared__ float s_w0[120], s_b0[32], s_w1[900], s_b1[32];
    __shared__ float s_wk[5760], s_bk[192];
    __shared__ float s_h0[8][33], s_h1[8][33], s_xs[8][8];

    const int t = threadIdx.x;
    for (int i = t; i < 120; i += 256) s_w0[i] = w0[i];
    for (int i = t; i < 900; i += 256) s_w1[i] = w1[i];
    for (int i = t; i < 5760; i += 256) s_wk[i] = wk[i];
    for (int i = t; i < 192; i += 256) s_bk[i] = bk[i];
    if (t < 30) { s_b0[t] = b0[t]; s_b1[t] = b1[t]; }
    __syncthreads();

    const int eg = t >> 5;
    const int lane = t & 31;

    for (int base = blockIdx.x * 8; base < E_EDGES; base += gridDim.x * 8) {
        const int eid = base + eg;
        const float4 ev = *(const float4*)(e + eid * 4);
        if (lane < 30) {
            float v = ev.x * s_w0[lane] + ev.y * s_w0[30 + lane]
                    + ev.z * s_w0[60 + lane] + ev.w * s_w0[90 + lane] + s_b0[lane];
            s_h0[eg][lane] = fmaxf(v, 0.f);
        }
        if (lane < 6) s_xs[eg][lane] = x[src[eid] * F_IN + lane];
        __syncthreads();
        if (lane < 30) {
            float v = s_b1[lane];
            #pragma unroll
            for (int k = 0; k < 30; ++k) v += s_h0[eg][k] * s_w1[k * 30 + lane];
            s_h1[eg][lane] = fmaxf(v, 0.f);
        }
        __syncthreads();
        const float x0 = s_xs[eg][0], x1v = s_xs[eg][1], x2v = s_xs[eg][2];
        const float x3v = s_xs[eg][3], x4v = s_xs[eg][4], x5v = s_xs[eg][5];
        float acc = x0 * s_bk[lane] + x1v * s_bk[32 + lane] + x2v * s_bk[64 + lane]
                  + x3v * s_bk[96 + lane] + x4v * s_bk[128 + lane] + x5v * s_bk[160 + lane];
        #pragma unroll 6
        for (int h = 0; h < 30; ++h) {
            const float* wr = s_wk + h * 192 + lane;
            float u = x0 * wr[0] + x1v * wr[32] + x2v * wr[64]
                    + x3v * wr[96] + x4v * wr[128] + x5v * wr[160];
            acc += s_h1[eg][h] * u;
        }
        atomicAdd(&agg1[tgt[eid] * C1 + lane], acc);
        __syncthreads();
    }
}

__global__ __launch_bounds__(256) void node_update1(
    const float* __restrict__ x, const float* __restrict__ root,
    const float* __restrict__ bias, float* __restrict__ buf)
{
    const int t = blockIdx.x * 256 + threadIdx.x;
    const int n = t >> 5, c = t & 31;
    const float* xr = x + n * F_IN;
    float v = buf[t] + bias[c];
    #pragma unroll
    for (int f = 0; f < F_IN; ++f) v += xr[f] * root[f * C1 + c];
    buf[t] = fmaxf(v, 0.f);
}

// ---------------------------------------------------------------------------
// Build WbT[col][k] bf16, col in [0,2048) = f*64+c, k in [0,32):
//   k<30 -> wk[k*2048+col]; k==30 -> bk[col] (bias row); k==31 -> 0.
// ---------------------------------------------------------------------------
__global__ __launch_bounds__(256) void wbt_build(
    const float* __restrict__ wk, const float* __restrict__ bk,
    short* __restrict__ wbt)
{
    const int tid = blockIdx.x * 256 + threadIdx.x;   // = col*32 + k
    const int col = tid >> 5, k = tid & 31;
    float v = (k < 30) ? wk[k * 2048 + col] : ((k == 30) ? bk[col] : 0.f);
    wbt[tid] = f2bf(v);
}

// ---------------------------------------------------------------------------
// ECC2 via MFMA. Per 256-thread block: 64 edges.
//  Phase A (fp32 VALU): edge MLP -> h1 (bf16 in LDS, rows 30=1,31=0), x1 tile.
//  Phase B: per wave w (16 edges): for each 256-col chunk (4 f x 64 c):
//    16x mfma_f32_16x16x32_bf16 (single K-step) -> K1 tile in regs (fp32),
//    then lane-local stage-2 contraction with fp32 x1 from LDS.
//  Scatter: atomicAdd per (edge, c2).
// ---------------------------------------------------------------------------
__global__ __launch_bounds__(256) void ecc2_mfma(
    const float* __restrict__ x1, const float* __restrict__ e,
    const int* __restrict__ src, const int* __restrict__ tgt,
    const float* __restrict__ w0, const float* __restrict__ b0,
    const float* __restrict__ w1, const float* __restrict__ b1,
    const short* __restrict__ wbt, float* __restrict__ agg2)
{
    __shared__ float s_w0[120], s_b0[32], s_w1[900], s_b1[32];
    __shared__ float s_h0[64][32];
    __shared__ float s_x1[64][32];
    __shared__ short s_h1b[64][32];

    const int t = threadIdx.x;
    for (int i = t; i < 120; i += 256) s_w0[i] = w0[i];
    for (int i = t; i < 900; i += 256) s_w1[i] = w1[i];
    if (t < 30) { s_b0[t] = b0[t]; s_b1[t] = b1[t]; }

    const int tile = blockIdx.x * 64;
    const int e_loc = t >> 2;      // 0..63
    const int p = t & 3;           // 0..3 -> j slice [p*8, p*8+8)
    const int eid = tile + e_loc;
    __syncthreads();

    // ---- phase A: MLP + stage x1[src] ----
    const float4 ev = *(const float4*)(e + eid * 4);
    #pragma unroll
    for (int i = 0; i < 8; ++i) {
        const int j = p * 8 + i;
        if (j < 30) {
            float v = ev.x * s_w0[j] + ev.y * s_w0[30 + j]
                    + ev.z * s_w0[60 + j] + ev.w * s_w0[90 + j] + s_b0[j];
            s_h0[e_loc][j] = fmaxf(v, 0.f);
        }
    }
    const int sb = src[eid] * C1;
    #pragma unroll
    for (int i = 0; i < 8; ++i) s_x1[e_loc][p * 8 + i] = x1[sb + p * 8 + i];
    __syncthreads();
    #pragma unroll
    for (int i = 0; i < 8; ++i) {
        const int j = p * 8 + i;
        short hb;
        if (j < 30) {
            float v = s_b1[j];
            #pragma unroll
            for (int k = 0; k < 30; ++k) v += s_h0[e_loc][k] * s_w1[k * 30 + j];
            hb = f2bf(fmaxf(v, 0.f));
        } else {
            hb = (j == 30) ? f2bf(1.0f) : (short)0;
        }
        s_h1b[e_loc][j] = hb;
    }
    __syncthreads();

    // ---- phase B ----
    const int wv = t >> 6;         // wave 0..3 -> edges [16*wv, 16*wv+16)
    const int lane = t & 63;
    const int n = lane & 15;       // output col within tile
    const int quad = lane >> 4;    // 0..3

    // A-frag: A[m=lane&15][k=quad*8+j] = h1b[16*wv+n][quad*8+j]
    const bf16x8 afrag = *(const bf16x8*)(&s_h1b[16 * wv + n][quad * 8]);

    float msg[4][4];               // [r][c_hi]
    #pragma unroll
    for (int r = 0; r < 4; ++r)
        #pragma unroll
        for (int c = 0; c < 4; ++c) msg[r][c] = 0.f;

    for (int ch = 0; ch < 8; ++ch) {
        // B-frag for tile tt: B[k=quad*8+j][n] = wbt[(ch*256 + tt*16 + n)*32 + quad*8 + j]
        const short* wb = wbt + ((size_t)(ch * 256 + n)) * 32 + quad * 8;
        f32x4 acc[16];
        #pragma unroll
        for (int tt = 0; tt < 16; ++tt) {
            const bf16x8 bfrag = *(const bf16x8*)(wb + (size_t)tt * 16 * 32);
            acc[tt] = __builtin_amdgcn_mfma_f32_16x16x32_bf16(
                afrag, bfrag, (f32x4){0.f, 0.f, 0.f, 0.f}, 0, 0, 0);
        }
        // stage 2: msg[r][chi] += x1[edge][4*ch+fl] * K1(acc[fl*4+chi][r])
        #pragma unroll
        for (int fl = 0; fl < 4; ++fl) {
            #pragma unroll
            for (int r = 0; r < 4; ++r) {
                const float xv = s_x1[16 * wv + quad * 4 + r][ch * 4 + fl];
                #pragma unroll
                for (int chi = 0; chi < 4; ++chi)
                    msg[r][chi] += xv * acc[fl * 4 + chi][r];
            }
        }
    }

    // ---- scatter ----
    #pragma unroll
    for (int r = 0; r < 4; ++r) {
        const int edge = tile + 16 * wv + quad * 4 + r;
        const int tb = tgt[edge] * C2;
        #pragma unroll
        for (int chi = 0; chi < 4; ++chi)
            atomicAdd(&agg2[tb + chi * 16 + n], msg[r][chi]);
    }
}

__global__ __launch_bounds__(256) void node_update2(
    const float* __restrict__ x1, const float* __restrict__ root,
    const float* __restrict__ bias, float* __restrict__ buf)
{
    const int t = blockIdx.x * 256 + threadIdx.x;
    const int n = t >> 6, c = t & 63;
    const float* xr = x1 + n * C1;
    float v = buf[t] + bias[c];
    #pragma unroll 8
    for (int k = 0; k < C1; ++k) v += xr[k] * root[k * C2 + c];
    buf[t] = fmaxf(v, 0.f);
}

__global__ __launch_bounds__(256) void xw_kernel(
    const float* __restrict__ x2, const float* __restrict__ W,
    float* __restrict__ xw)
{
    const int t = blockIdx.x * 256 + threadIdx.x;
    const int n = t >> 5, c = t & 31;
    const float* xr = x2 + n * C2;
    float v = 0.f;
    #pragma unroll 8
    for (int k = 0; k < C2; ++k) v += xr[k] * W[k * C3 + c];
    xw[t] = v;
}

__global__ __launch_bounds__(256) void gcn_scatter(
    const float* __restrict__ xw, const int* __restrict__ gs,
    const int* __restrict__ gt, const float* __restrict__ gw,
    float* __restrict__ agg3)
{
    const int t = blockIdx.x * 256 + threadIdx.x;
    const int i = t >> 5, lane = t & 31;
    const float v = gw[i] * xw[gs[i] * C3 + lane];
    atomicAdd(&agg3[gt[i] * C3 + lane], v);
}

__global__ __launch_bounds__(256) void final_pool(
    const float* __restrict__ agg3, const float* __restrict__ gb,
    const int* __restrict__ seg, float* __restrict__ out)
{
    const int t = blockIdx.x * 256 + threadIdx.x;
    const int n = t >> 5, c = t & 31;
    const float v = fmaxf(agg3[t] + gb[c], 0.f);
    atomicAdd(&out[seg[n] * C3 + c], v);
}

extern "C" void kernel_launch(void* const* d_in, const int* in_sizes, int n_in,
                              void* d_out, int out_size, void* d_ws, size_t ws_size,
                              hipStream_t stream)
{
    const float* x       = (const float*)d_in[0];
    const float* e       = (const float*)d_in[1];
    const int*   src     = (const int*)d_in[2];
    const int*   tgt     = (const int*)d_in[3];
    const int*   seg     = (const int*)d_in[4];
    const int*   gcn_src = (const int*)d_in[5];
    const int*   gcn_tgt = (const int*)d_in[6];
    const float* gcn_w   = (const float*)d_in[7];
    const float* e1_w0   = (const float*)d_in[8];
    const float* e1_b0   = (const float*)d_in[9];
    const float* e1_w1   = (const float*)d_in[10];
    const float* e1_b1   = (const float*)d_in[11];
    const float* e1_wk   = (const float*)d_in[12];
    const float* e1_bk   = (const float*)d_in[13];
    const float* e1_root = (const float*)d_in[14];
    const float* e1_bias = (const float*)d_in[15];
    const float* e2_w0   = (const float*)d_in[16];
    const float* e2_b0   = (const float*)d_in[17];
    const float* e2_w1   = (const float*)d_in[18];
    const float* e2_b1   = (const float*)d_in[19];
    const float* e2_wk   = (const float*)d_in[20];
    const float* e2_bk   = (const float*)d_in[21];
    const float* e2_root = (const float*)d_in[22];
    const float* e2_bias = (const float*)d_in[23];
    const float* gcn_W   = (const float*)d_in[24];
    const float* gcn_b   = (const float*)d_in[25];
    float* out = (float*)d_out;

    float* ws   = (float*)d_ws;
    float* buf1 = ws;                                  // agg1 -> x1   [N, C1]
    float* buf2 = ws + N_NODES * C1;                   // agg2 -> x2   [N, C2]
    float* bxw  = ws + N_NODES * (C1 + C2);            // xw           [N, C3]
    float* buf3 = ws + N_NODES * (C1 + C2 + C3);       // agg3         [N, C3]
    short* wbt  = (short*)(ws + N_NODES * (C1 + C2 + C3 + C3));  // [2048*32] bf16

    hipMemsetAsync(buf1, 0, (size_t)N_NODES * C1 * sizeof(float), stream);
    hipMemsetAsync(buf2, 0, (size_t)N_NODES * C2 * sizeof(float), stream);
    hipMemsetAsync(buf3, 0, (size_t)N_NODES * C3 * sizeof(float), stream);
    hipMemsetAsync(out, 0, (size_t)out_size * sizeof(float), stream);

    wbt_build<<<(2048 * 32) / 256, 256, 0, stream>>>(e2_wk, e2_bk, wbt);

    ecc1_edges<<<2048, 256, 0, stream>>>(x, e, src, tgt,
        e1_w0, e1_b0, e1_w1, e1_b1, e1_wk, e1_bk, buf1);
    node_update1<<<(N_NODES * C1) / 256, 256, 0, stream>>>(x, e1_root, e1_bias, buf1);
    ecc2_mfma<<<E_EDGES / 64, 256, 0, stream>>>(buf1, e, src, tgt,
        e2_w0, e2_b0, e2_w1, e2_b1, wbt, buf2);
    node_update2<<<(N_NODES * C2) / 256, 256, 0, stream>>>(buf1, e2_root, e2_bias, buf2);
    xw_kernel<<<(N_NODES * C3) / 256, 256, 0, stream>>>(buf2, gcn_W, bxw);
    gcn_scatter<<<((E_EDGES + N_NODES) * C3) / 256, 256, 0, stream>>>(
        bxw, gcn_src, gcn_tgt, gcn_w, buf3);
    final_pool<<<(N_NODES * C3) / 256, 256, 0, stream>>>(buf3, gcn_b, seg, out);
}

// Round 3
// 257.092 us; speedup vs baseline: 2.1081x; 1.2639x over previous
//
#include <hip/hip_runtime.h>
#include <hip/hip_bf16.h>

#define N_NODES 16384
#define E_EDGES 131072
#define F_IN 6
#define S_DIM 4
#define G_GRAPHS 256
#define H_DIM 30
#define C1 32
#define C2 64
#define C3 32

typedef __attribute__((ext_vector_type(8))) short bf16x8;
typedef __attribute__((ext_vector_type(4))) float f32x4;

__device__ __forceinline__ short f2bf(float f) {
    union { float f; unsigned u; } a; a.f = f;
    unsigned r = a.u + 0x7FFFu + ((a.u >> 16) & 1u);
    return (short)(r >> 16);
}

// async global->LDS 16B per lane; lds base must be wave-uniform.
__device__ __forceinline__ void async_copy16(const void* g, void* l) {
    __builtin_amdgcn_global_load_lds(
        (const __attribute__((address_space(1))) unsigned int*)g,
        (__attribute__((address_space(3))) unsigned int*)l, 16, 0, 0);
}

// ---------------------------------------------------------------------------
// Swizzled bf16 weight builders.
// ecc2: wbt2[ch 8][kq 4][cl 256][j 8]; value W'[k = kq*8+j][col = ch*256+cl]
//       k<30 -> wk[k*2048+col]; k==30 -> bk[col]; k==31 -> 0
// ---------------------------------------------------------------------------
__global__ __launch_bounds__(256) void wbt2_build(
    const float* __restrict__ wk, const float* __restrict__ bk,
    short* __restrict__ dst)
{
    const int tid = blockIdx.x * 256 + threadIdx.x;   // col*32 + k
    const int col = tid >> 5, k = tid & 31;
    const int ch = col >> 8, cl = col & 255, kq = k >> 3, j = k & 7;
    float v = (k < 30) ? wk[k * 2048 + col] : ((k == 30) ? bk[col] : 0.f);
    dst[((ch * 4 + kq) * 256 + cl) * 8 + j] = f2bf(v);
}

// ecc1: wbt1[kq 4][col 192][j 8]; value W'[k][col], k<30->wk, 30->bk, 31->0
__global__ __launch_bounds__(256) void wbt1_build(
    const float* __restrict__ wk, const float* __restrict__ bk,
    short* __restrict__ dst)
{
    const int tid = blockIdx.x * 256 + threadIdx.x;   // col*32 + k
    const int col = tid >> 5, k = tid & 31;
    float v = (k < 30) ? wk[k * 192 + col] : ((k == 30) ? bk[col] : 0.f);
    dst[((k >> 3) * 192 + col) * 8 + (k & 7)] = f2bf(v);
}

// ---------------------------------------------------------------------------
// ECC1 via MFMA. 128 edges/block. K1[e, f*32+c1] = [128,32]@[32,192] MFMA,
// stage-2 over f (6) in fp32 VALU, atomic scatter to agg1.
// ---------------------------------------------------------------------------
__global__ __launch_bounds__(256, 2) void ecc1_mfma(
    const float* __restrict__ x, const float* __restrict__ e,
    const int* __restrict__ src, const int* __restrict__ tgt,
    const float* __restrict__ w0, const float* __restrict__ b0,
    const float* __restrict__ w1, const float* __restrict__ b1,
    const short* __restrict__ wbt1, float* __restrict__ agg1)
{
    __shared__ short s_wbt[6144];         // [kq4][192][8]  12.3 KB
    __shared__ short s_h1b[128 * 40];     // stride 40 shorts (80B, 16-aligned)
    __shared__ float s_x[128 * 9];        // stride 9 floats (bank-spread)
    __shared__ float s_w0[120], s_b0[32], s_w1[900], s_b1[32];

    const int t = threadIdx.x;
    const int tile = blockIdx.x * 128;

    // stage wbt1: 12288 B = 3 rounds x (4 waves x 1 KB)
    {
        const int wv = t >> 6, lane = t & 63;
        #pragma unroll
        for (int r = 0; r < 3; ++r) {
            const int off = r * 2048 + wv * 512;      // shorts
            async_copy16(wbt1 + off + lane * 8, s_wbt + off);
        }
    }
    for (int i = t; i < 120; i += 256) s_w0[i] = w0[i];
    for (int i = t; i < 900; i += 256) s_w1[i] = w1[i];
    if (t < 30) { s_b0[t] = b0[t]; s_b1[t] = b1[t]; }
    __syncthreads();

    // ---- phase A ----
    if (t < 128) {
        const int eid = tile + t;
        const float4 ev = *(const float4*)(e + eid * 4);
        float h0[30];
        #pragma unroll
        for (int j = 0; j < 30; ++j) {
            float v = ev.x * s_w0[j] + ev.y * s_w0[30 + j]
                    + ev.z * s_w0[60 + j] + ev.w * s_w0[90 + j] + s_b0[j];
            h0[j] = fmaxf(v, 0.f);
        }
        short hh[32];
        #pragma unroll
        for (int j = 0; j < 30; ++j) {
            float v = s_b1[j];
            #pragma unroll
            for (int k = 0; k < 30; ++k) v += h0[k] * s_w1[k * 30 + j];
            hh[j] = f2bf(fmaxf(v, 0.f));
        }
        hh[30] = (short)0x3F80;  // 1.0 bf16 (bias row)
        hh[31] = 0;
        #pragma unroll
        for (int q = 0; q < 4; ++q) {
            bf16x8 v;
            #pragma unroll
            for (int i2 = 0; i2 < 8; ++i2) v[i2] = hh[q * 8 + i2];
            *(bf16x8*)&s_h1b[t * 40 + q * 8] = v;
        }
    } else {
        const int i = t - 128;
        const float2* xp = (const float2*)(x + (size_t)src[tile + i] * F_IN);
        const float2 a = xp[0], b = xp[1], c = xp[2];
        float* d = s_x + i * 9;
        d[0] = a.x; d[1] = a.y; d[2] = b.x; d[3] = b.y; d[4] = c.x; d[5] = c.y;
    }
    __syncthreads();

    // ---- phase B: wave -> 32 edges (2 m-tiles) ----
    const int wv = t >> 6, lane = t & 63;
    const int n = lane & 15, quad = lane >> 4;
    const int e0 = wv * 32;

    const bf16x8 af0 = *(const bf16x8*)&s_h1b[(e0 + n) * 40 + quad * 8];
    const bf16x8 af1 = *(const bf16x8*)&s_h1b[(e0 + 16 + n) * 40 + quad * 8];

    const short* wb = s_wbt + quad * 1536 + n * 8;
    f32x4 a0[12], a1[12];
    #pragma unroll
    for (int tt = 0; tt < 12; ++tt) {
        const bf16x8 bfv = *(const bf16x8*)(wb + tt * 128);
        a0[tt] = __builtin_amdgcn_mfma_f32_16x16x32_bf16(af0, bfv, (f32x4){0.f,0.f,0.f,0.f}, 0, 0, 0);
        a1[tt] = __builtin_amdgcn_mfma_f32_16x16x32_bf16(af1, bfv, (f32x4){0.f,0.f,0.f,0.f}, 0, 0, 0);
    }

    float msg0[4][2], msg1[4][2];
    #pragma unroll
    for (int r = 0; r < 4; ++r) { msg0[r][0]=msg0[r][1]=msg1[r][0]=msg1[r][1]=0.f; }

    #pragma unroll
    for (int tt = 0; tt < 12; ++tt) {
        const int f = tt >> 1, h = tt & 1;
        #pragma unroll
        for (int r = 0; r < 4; ++r) {
            msg0[r][h] += s_x[(e0 + quad * 4 + r) * 9 + f] * a0[tt][r];
            msg1[r][h] += s_x[(e0 + 16 + quad * 4 + r) * 9 + f] * a1[tt][r];
        }
    }

    #pragma unroll
    for (int r = 0; r < 4; ++r) {
        const int tb0 = tgt[tile + e0 + quad * 4 + r] * C1;
        atomicAdd(&agg1[tb0 + n], msg0[r][0]);
        atomicAdd(&agg1[tb0 + 16 + n], msg0[r][1]);
        const int tb1 = tgt[tile + e0 + 16 + quad * 4 + r] * C1;
        atomicAdd(&agg1[tb1 + n], msg1[r][0]);
        atomicAdd(&agg1[tb1 + 16 + n], msg1[r][1]);
    }
}

__global__ __launch_bounds__(256) void node_update1(
    const float* __restrict__ x, const float* __restrict__ root,
    const float* __restrict__ bias, float* __restrict__ buf)
{
    const int t = blockIdx.x * 256 + threadIdx.x;
    const int n = t >> 5, c = t & 31;
    const float* xr = x + n * F_IN;
    float v = buf[t] + bias[c];
    #pragma unroll
    for (int f = 0; f < F_IN; ++f) v += xr[f] * root[f * C1 + c];
    buf[t] = fmaxf(v, 0.f);
}

// ---------------------------------------------------------------------------
// ECC2 via MFMA. 128 edges/block; wbt chunks (16 KB) double-buffered in LDS
// shared by all 4 waves; each wave: 2 m-tiles, bfrag reused across both.
// ---------------------------------------------------------------------------
__global__ __launch_bounds__(256, 2) void ecc2_mfma(
    const float* __restrict__ x1, const float* __restrict__ e,
    const int* __restrict__ src, const int* __restrict__ tgt,
    const float* __restrict__ w0, const float* __restrict__ b0,
    const float* __restrict__ w1, const float* __restrict__ b1,
    const short* __restrict__ wbt2, float* __restrict__ agg2)
{
    __shared__ short s_wbt[2 * 8192];     // dbuf, chunk = [kq4][256][8] 16 KB
    __shared__ short s_h1b[128 * 40];     // stride 40 shorts
    __shared__ float s_x1[128 * 36];      // stride 36 floats (144B, 16-aligned)
    __shared__ float s_w0[120], s_b0[32], s_w1[900], s_b1[32];

    const int t = threadIdx.x;
    const int tile = blockIdx.x * 128;
    const int wv = t >> 6, lane = t & 63;

    // prefetch chunk 0
    {
        #pragma unroll
        for (int r = 0; r < 4; ++r) {
            const int off = r * 2048 + wv * 512;    // shorts
            async_copy16(wbt2 + off + lane * 8, s_wbt + off);
        }
    }
    for (int i = t; i < 120; i += 256) s_w0[i] = w0[i];
    for (int i = t; i < 900; i += 256) s_w1[i] = w1[i];
    if (t < 30) { s_b0[t] = b0[t]; s_b1[t] = b1[t]; }
    __syncthreads();

    // ---- phase A ----
    if (t < 128) {
        const int eid = tile + t;
        const float4 ev = *(const float4*)(e + eid * 4);
        float h0[30];
        #pragma unroll
        for (int j = 0; j < 30; ++j) {
            float v = ev.x * s_w0[j] + ev.y * s_w0[30 + j]
                    + ev.z * s_w0[60 + j] + ev.w * s_w0[90 + j] + s_b0[j];
            h0[j] = fmaxf(v, 0.f);
        }
        short hh[32];
        #pragma unroll
        for (int j = 0; j < 30; ++j) {
            float v = s_b1[j];
            #pragma unroll
            for (int k = 0; k < 30; ++k) v += h0[k] * s_w1[k * 30 + j];
            hh[j] = f2bf(fmaxf(v, 0.f));
        }
        hh[30] = (short)0x3F80;
        hh[31] = 0;
        #pragma unroll
        for (int q = 0; q < 4; ++q) {
            bf16x8 v;
            #pragma unroll
            for (int i2 = 0; i2 < 8; ++i2) v[i2] = hh[q * 8 + i2];
            *(bf16x8*)&s_h1b[t * 40 + q * 8] = v;
        }
    } else {
        const int i = t - 128;
        const float* xp = x1 + (size_t)src[tile + i] * C1;
        #pragma unroll
        for (int q = 0; q < 8; ++q) {
            const float4 v = *(const float4*)(xp + q * 4);
            *(float4*)&s_x1[i * 36 + q * 4] = v;
        }
    }
    __syncthreads();

    // ---- phase B ----
    const int n = lane & 15, quad = lane >> 4;
    const int e0 = wv * 32;

    const bf16x8 af0 = *(const bf16x8*)&s_h1b[(e0 + n) * 40 + quad * 8];
    const bf16x8 af1 = *(const bf16x8*)&s_h1b[(e0 + 16 + n) * 40 + quad * 8];

    float msg0[4][4], msg1[4][4];
    #pragma unroll
    for (int r = 0; r < 4; ++r)
        #pragma unroll
        for (int c = 0; c < 4; ++c) { msg0[r][c] = 0.f; msg1[r][c] = 0.f; }

    for (int ch = 0; ch < 8; ++ch) {
        if (ch < 7) {   // prefetch next chunk into other buffer
            const int nb = (ch + 1) & 1;
            #pragma unroll
            for (int r = 0; r < 4; ++r) {
                const int off = r * 2048 + wv * 512;
                async_copy16(wbt2 + (ch + 1) * 8192 + off + lane * 8,
                             s_wbt + nb * 8192 + off);
            }
        }
        const short* wb = s_wbt + (ch & 1) * 8192 + quad * 2048 + n * 8;
        f32x4 a0[16], a1[16];
        #pragma unroll
        for (int tt = 0; tt < 16; ++tt) {
            const bf16x8 bfv = *(const bf16x8*)(wb + tt * 128);
            a0[tt] = __builtin_amdgcn_mfma_f32_16x16x32_bf16(af0, bfv, (f32x4){0.f,0.f,0.f,0.f}, 0, 0, 0);
            a1[tt] = __builtin_amdgcn_mfma_f32_16x16x32_bf16(af1, bfv, (f32x4){0.f,0.f,0.f,0.f}, 0, 0, 0);
        }
        // stage 2: col = ch*256 + tt*16 + n; f = ch*4 + (tt>>2); c2 = (tt&3)*16+n
        #pragma unroll
        for (int fl = 0; fl < 4; ++fl) {
            #pragma unroll
            for (int r = 0; r < 4; ++r) {
                const float xv0 = s_x1[(e0 + quad * 4 + r) * 36 + ch * 4 + fl];
                const float xv1 = s_x1[(e0 + 16 + quad * 4 + r) * 36 + ch * 4 + fl];
                #pragma unroll
                for (int chi = 0; chi < 4; ++chi) {
                    msg0[r][chi] += xv0 * a0[fl * 4 + chi][r];
                    msg1[r][chi] += xv1 * a1[fl * 4 + chi][r];
                }
            }
        }
        __syncthreads();
    }

    // ---- scatter ----
    #pragma unroll
    for (int r = 0; r < 4; ++r) {
        const int tb0 = tgt[tile + e0 + quad * 4 + r] * C2;
        #pragma unroll
        for (int chi = 0; chi < 4; ++chi)
            atomicAdd(&agg2[tb0 + chi * 16 + n], msg0[r][chi]);
        const int tb1 = tgt[tile + e0 + 16 + quad * 4 + r] * C2;
        #pragma unroll
        for (int chi = 0; chi < 4; ++chi)
            atomicAdd(&agg2[tb1 + chi * 16 + n], msg1[r][chi]);
    }
}

__global__ __launch_bounds__(256) void node_update2(
    const float* __restrict__ x1, const float* __restrict__ root,
    const float* __restrict__ bias, float* __restrict__ buf)
{
    const int t = blockIdx.x * 256 + threadIdx.x;
    const int n = t >> 6, c = t & 63;
    const float* xr = x1 + n * C1;
    float v = buf[t] + bias[c];
    #pragma unroll 8
    for (int k = 0; k < C1; ++k) v += xr[k] * root[k * C2 + c];
    buf[t] = fmaxf(v, 0.f);
}

__global__ __launch_bounds__(256) void xw_kernel(
    const float* __restrict__ x2, const float* __restrict__ W,
    float* __restrict__ xw)
{
    const int t = blockIdx.x * 256 + threadIdx.x;
    const int n = t >> 5, c = t & 31;
    const float* xr = x2 + n * C2;
    float v = 0.f;
    #pragma unroll 8
    for (int k = 0; k < C2; ++k) v += xr[k] * W[k * C3 + c];
    xw[t] = v;
}

__global__ __launch_bounds__(256) void gcn_scatter(
    const float* __restrict__ xw, const int* __restrict__ gs,
    const int* __restrict__ gt, const float* __restrict__ gw,
    float* __restrict__ agg3)
{
    const int t = blockIdx.x * 256 + threadIdx.x;
    const int i = t >> 5, lane = t & 31;
    const float v = gw[i] * xw[gs[i] * C3 + lane];
    atomicAdd(&agg3[gt[i] * C3 + lane], v);
}

__global__ __launch_bounds__(256) void final_pool(
    const float* __restrict__ agg3, const float* __restrict__ gb,
    const int* __restrict__ seg, float* __restrict__ out)
{
    const int t = blockIdx.x * 256 + threadIdx.x;
    const int n = t >> 5, c = t & 31;
    const float v = fmaxf(agg3[t] + gb[c], 0.f);
    atomicAdd(&out[seg[n] * C3 + c], v);
}

extern "C" void kernel_launch(void* const* d_in, const int* in_sizes, int n_in,
                              void* d_out, int out_size, void* d_ws, size_t ws_size,
                              hipStream_t stream)
{
    const float* x       = (const float*)d_in[0];
    const float* e       = (const float*)d_in[1];
    const int*   src     = (const int*)d_in[2];
    const int*   tgt     = (const int*)d_in[3];
    const int*   seg     = (const int*)d_in[4];
    const int*   gcn_src = (const int*)d_in[5];
    const int*   gcn_tgt = (const int*)d_in[6];
    const float* gcn_w   = (const float*)d_in[7];
    const float* e1_w0   = (const float*)d_in[8];
    const float* e1_b0   = (const float*)d_in[9];
    const float* e1_w1   = (const float*)d_in[10];
    const float* e1_b1   = (const float*)d_in[11];
    const float* e1_wk   = (const float*)d_in[12];
    const float* e1_bk   = (const float*)d_in[13];
    const float* e1_root = (const float*)d_in[14];
    const float* e1_bias = (const float*)d_in[15];
    const float* e2_w0   = (const float*)d_in[16];
    const float* e2_b0   = (const float*)d_in[17];
    const float* e2_w1   = (const float*)d_in[18];
    const float* e2_b1   = (const float*)d_in[19];
    const float* e2_wk   = (const float*)d_in[20];
    const float* e2_bk   = (const float*)d_in[21];
    const float* e2_root = (const float*)d_in[22];
    const float* e2_bias = (const float*)d_in[23];
    const float* gcn_W   = (const float*)d_in[24];
    const float* gcn_b   = (const float*)d_in[25];
    float* out = (float*)d_out;

    float* ws   = (float*)d_ws;
    float* buf1 = ws;                                  // agg1 -> x1   [N, C1]
    float* buf2 = ws + N_NODES * C1;                   // agg2 -> x2   [N, C2]
    float* bxw  = ws + N_NODES * (C1 + C2);            // xw           [N, C3]
    float* buf3 = ws + N_NODES * (C1 + C2 + C3);       // agg3         [N, C3]
    short* wbt2 = (short*)(ws + N_NODES * (C1 + C2 + C3 + C3));  // 65536 bf16
    short* wbt1 = wbt2 + 65536;                        // 6144 bf16

    hipMemsetAsync(buf1, 0, (size_t)N_NODES * C1 * sizeof(float), stream);
    hipMemsetAsync(buf2, 0, (size_t)N_NODES * C2 * sizeof(float), stream);
    hipMemsetAsync(buf3, 0, (size_t)N_NODES * C3 * sizeof(float), stream);
    hipMemsetAsync(out, 0, (size_t)out_size * sizeof(float), stream);

    wbt2_build<<<(2048 * 32) / 256, 256, 0, stream>>>(e2_wk, e2_bk, wbt2);
    wbt1_build<<<(192 * 32) / 256, 256, 0, stream>>>(e1_wk, e1_bk, wbt1);

    ecc1_mfma<<<E_EDGES / 128, 256, 0, stream>>>(x, e, src, tgt,
        e1_w0, e1_b0, e1_w1, e1_b1, wbt1, buf1);
    node_update1<<<(N_NODES * C1) / 256, 256, 0, stream>>>(x, e1_root, e1_bias, buf1);
    ecc2_mfma<<<E_EDGES / 128, 256, 0, stream>>>(buf1, e, src, tgt,
        e2_w0, e2_b0, e2_w1, e2_b1, wbt2, buf2);
    node_update2<<<(N_NODES * C2) / 256, 256, 0, stream>>>(buf1, e2_root, e2_bias, buf2);
    xw_kernel<<<(N_NODES * C3) / 256, 256, 0, stream>>>(buf2, gcn_W, bxw);
    gcn_scatter<<<((E_EDGES + N_NODES) * C3) / 256, 256, 0, stream>>>(
        bxw, gcn_src, gcn_tgt, gcn_w, buf3);
    final_pool<<<(N_NODES * C3) / 256, 256, 0, stream>>>(buf3, gcn_b, seg, out);
}

// Round 4
// 228.183 us; speedup vs baseline: 2.3752x; 1.1267x over previous
//
#include <hip/hip_runtime.h>
#include <hip/hip_bf16.h>

#define N_NODES 16384
#define E_EDGES 131072
#define F_IN 6
#define S_DIM 4
#define G_GRAPHS 256
#define H_DIM 30
#define C1 32
#define C2 64
#define C3 32

typedef __attribute__((ext_vector_type(8))) short bf16x8;
typedef __attribute__((ext_vector_type(4))) float f32x4;

__device__ __forceinline__ short f2bf(float f) {
    union { float f; unsigned u; } a; a.f = f;
    unsigned r = a.u + 0x7FFFu + ((a.u >> 16) & 1u);
    return (short)(r >> 16);
}

// pack two f32 -> two bf16 (round-half-up), 3 VALU ops
__device__ __forceinline__ unsigned pack2(float a, float b) {
    unsigned ua = __float_as_uint(a) + 0x8000u;
    unsigned ub = __float_as_uint(b) + 0x8000u;
    return __builtin_amdgcn_perm(ub, ua, 0x07060302u);
}

// ---------------------------------------------------------------------------
// Combined weight builder.
// wbt2[kc 32][nt 4][n 16][kq 4][j 8] = W2'[K=kc*32+kq*8+j][c2=nt*16+n]
//   where K -> (h=kc, c1=kq*8+j); h<30 -> wk2, h==30 -> bk2, h==31 -> 0
// wbt1[kc 8][nt 2][n 16][kq 4][j 8] = W1'[...], h=kc*4+kq, f=j(<6), c1=nt*16+n
// ---------------------------------------------------------------------------
__global__ __launch_bounds__(256) void build_wbt(
    const float* __restrict__ wk2, const float* __restrict__ bk2,
    const float* __restrict__ wk1, const float* __restrict__ bk1,
    short* __restrict__ wbt2, short* __restrict__ wbt1)
{
    const int idx = blockIdx.x * 256 + threadIdx.x;
    if (idx < 65536) {
        const int j = idx & 7, kq = (idx >> 3) & 3, n = (idx >> 5) & 15;
        const int nt = (idx >> 9) & 3, kc = idx >> 11;
        const int c1 = kq * 8 + j, c2 = nt * 16 + n;
        float v = (kc < 30) ? wk2[kc * 2048 + c1 * 64 + c2]
                            : ((kc == 30) ? bk2[c1 * 64 + c2] : 0.f);
        wbt2[idx] = f2bf(v);
    } else {
        const int i2 = idx - 65536;
        const int j = i2 & 7, kq = (i2 >> 3) & 3, n = (i2 >> 5) & 15;
        const int nt = (i2 >> 9) & 1, kc = i2 >> 10;
        const int h = kc * 4 + kq, c1 = nt * 16 + n;
        float v = 0.f;
        if (j < 6) {
            if (h < 30) v = wk1[h * 192 + j * 32 + c1];
            else if (h == 30) v = bk1[j * 32 + c1];
        }
        wbt1[i2] = f2bf(v);
    }
}

// ---------------------------------------------------------------------------
// ECC1: outer-product GEMM  msg = (h1 ⊗ x_pad8) @ W1'  [E,256]@[256,32].
// 256 edges/block (1 edge/thread MLP), 4 waves x 4 m-tiles, B from L2.
// ---------------------------------------------------------------------------
__global__ __launch_bounds__(256, 2) void ecc1_mfma(
    const float* __restrict__ x, const float* __restrict__ e,
    const int* __restrict__ src, const int* __restrict__ tgt,
    const float* __restrict__ w0, const float* __restrict__ b0,
    const float* __restrict__ w1, const float* __restrict__ b1,
    const short* __restrict__ wbt1, float* __restrict__ agg1)
{
    __shared__ unsigned short s_h1b[256 * 40];
    __shared__ unsigned short s_xb[256 * 8];
    __shared__ float s_w0[120], s_b0[30], s_w1[900], s_b1[30];

    const int t = threadIdx.x;
    const int tile = blockIdx.x * 256;
    for (int i = t; i < 120; i += 256) s_w0[i] = w0[i];
    for (int i = t; i < 900; i += 256) s_w1[i] = w1[i];
    if (t < 30) { s_b0[t] = b0[t]; s_b1[t] = b1[t]; }
    __syncthreads();

    // ---- phase A: per-thread edge MLP + x staging ----
    {
        const int eid = tile + t;
        const float4 ev = *(const float4*)(e + eid * 4);
        float h0[30];
        #pragma unroll
        for (int j = 0; j < 30; ++j) {
            float v = ev.x * s_w0[j] + ev.y * s_w0[30 + j]
                    + ev.z * s_w0[60 + j] + ev.w * s_w0[90 + j] + s_b0[j];
            h0[j] = fmaxf(v, 0.f);
        }
        unsigned hw[16];
        #pragma unroll
        for (int i = 0; i < 15; ++i) {
            float va = s_b1[2 * i], vb = s_b1[2 * i + 1];
            #pragma unroll
            for (int k = 0; k < 30; ++k) {
                va += h0[k] * s_w1[k * 30 + 2 * i];
                vb += h0[k] * s_w1[k * 30 + 2 * i + 1];
            }
            hw[i] = pack2(fmaxf(va, 0.f), fmaxf(vb, 0.f));
        }
        hw[15] = pack2(1.0f, 0.f);   // bias row h=30, zero row h=31
        uint4* hb = (uint4*)&s_h1b[t * 40];
        hb[0] = make_uint4(hw[0], hw[1], hw[2], hw[3]);
        hb[1] = make_uint4(hw[4], hw[5], hw[6], hw[7]);
        hb[2] = make_uint4(hw[8], hw[9], hw[10], hw[11]);
        hb[3] = make_uint4(hw[12], hw[13], hw[14], hw[15]);

        const float2* xp = (const float2*)(x + (size_t)src[eid] * F_IN);
        const float2 a = xp[0], b = xp[1], c = xp[2];
        *(uint4*)&s_xb[t * 8] =
            make_uint4(pack2(a.x, a.y), pack2(b.x, b.y), pack2(c.x, c.y), 0u);
    }
    __syncthreads();

    // ---- compute ----
    const int wv = t >> 6, lane = t & 63;
    const int n = lane & 15, quad = lane >> 4;
    const int e0 = wv * 64;

    float xf[4][8];
    #pragma unroll
    for (int m = 0; m < 4; ++m) {
        const uint4 xv = *(const uint4*)&s_xb[(e0 + m * 16 + n) * 8];
        xf[m][0] = __uint_as_float(xv.x << 16);
        xf[m][1] = __uint_as_float(xv.x & 0xFFFF0000u);
        xf[m][2] = __uint_as_float(xv.y << 16);
        xf[m][3] = __uint_as_float(xv.y & 0xFFFF0000u);
        xf[m][4] = __uint_as_float(xv.z << 16);
        xf[m][5] = __uint_as_float(xv.z & 0xFFFF0000u);
        xf[m][6] = 0.f; xf[m][7] = 0.f;
    }

    f32x4 acc[4][2];
    #pragma unroll
    for (int m = 0; m < 4; ++m)
        #pragma unroll
        for (int nt = 0; nt < 2; ++nt) acc[m][nt] = (f32x4){0.f, 0.f, 0.f, 0.f};

    #pragma unroll
    for (int kc = 0; kc < 8; ++kc) {
        bf16x8 bfr[2];
        #pragma unroll
        for (int nt = 0; nt < 2; ++nt)
            bfr[nt] = *(const bf16x8*)(wbt1 + (((kc * 2 + nt) * 16 + n) << 5) + quad * 8);
        #pragma unroll
        for (int m = 0; m < 4; ++m) {
            const unsigned hv = s_h1b[(e0 + m * 16 + n) * 40 + kc * 4 + quad];
            const float hf = __uint_as_float(hv << 16);
            union { unsigned u[4]; bf16x8 v; } af;
            #pragma unroll
            for (int i = 0; i < 4; ++i)
                af.u[i] = pack2(hf * xf[m][2 * i], hf * xf[m][2 * i + 1]);
            acc[m][0] = __builtin_amdgcn_mfma_f32_16x16x32_bf16(af.v, bfr[0], acc[m][0], 0, 0, 0);
            acc[m][1] = __builtin_amdgcn_mfma_f32_16x16x32_bf16(af.v, bfr[1], acc[m][1], 0, 0, 0);
        }
    }

    #pragma unroll
    for (int m = 0; m < 4; ++m)
        #pragma unroll
        for (int r = 0; r < 4; ++r) {
            const int tb = tgt[tile + e0 + m * 16 + quad * 4 + r] * C1;
            atomicAdd(&agg1[tb + n], acc[m][0][r]);
            atomicAdd(&agg1[tb + 16 + n], acc[m][1][r]);
        }
}

__global__ __launch_bounds__(256) void node_update1(
    const float* __restrict__ x, const float* __restrict__ root,
    const float* __restrict__ bias, float* __restrict__ buf)
{
    const int t = blockIdx.x * 256 + threadIdx.x;
    const int n = t >> 5, c = t & 31;
    const float* xr = x + n * F_IN;
    float v = buf[t] + bias[c];
    #pragma unroll
    for (int f = 0; f < F_IN; ++f) v += xr[f] * root[f * C1 + c];
    buf[t] = fmaxf(v, 0.f);
}

// ---------------------------------------------------------------------------
// ECC2: outer-product GEMM  msg = (h1 ⊗ x1) @ W2'  [E,1024]@[1024,64].
// 256 edges/block, 4 waves x 4 m-tiles x 4 n-tiles, B streamed from L2,
// A built on the fly (scalar h1[kc] x cached x1 fragment). 2 barriers total.
// ---------------------------------------------------------------------------
__global__ __launch_bounds__(256, 2) void ecc2_mfma(
    const float* __restrict__ x1, const float* __restrict__ e,
    const int* __restrict__ src, const int* __restrict__ tgt,
    const float* __restrict__ w0, const float* __restrict__ b0,
    const float* __restrict__ w1, const float* __restrict__ b1,
    const short* __restrict__ wbt2, float* __restrict__ agg2)
{
    __shared__ unsigned short s_h1b[256 * 40];
    __shared__ unsigned short s_x1b[256 * 40];
    __shared__ float s_w0[120], s_b0[30], s_w1[900], s_b1[30];

    const int t = threadIdx.x;
    const int tile = blockIdx.x * 256;
    for (int i = t; i < 120; i += 256) s_w0[i] = w0[i];
    for (int i = t; i < 900; i += 256) s_w1[i] = w1[i];
    if (t < 30) { s_b0[t] = b0[t]; s_b1[t] = b1[t]; }
    __syncthreads();

    // ---- phase A ----
    {
        const int eid = tile + t;
        const float4 ev = *(const float4*)(e + eid * 4);
        float h0[30];
        #pragma unroll
        for (int j = 0; j < 30; ++j) {
            float v = ev.x * s_w0[j] + ev.y * s_w0[30 + j]
                    + ev.z * s_w0[60 + j] + ev.w * s_w0[90 + j] + s_b0[j];
            h0[j] = fmaxf(v, 0.f);
        }
        unsigned hw[16];
        #pragma unroll
        for (int i = 0; i < 15; ++i) {
            float va = s_b1[2 * i], vb = s_b1[2 * i + 1];
            #pragma unroll
            for (int k = 0; k < 30; ++k) {
                va += h0[k] * s_w1[k * 30 + 2 * i];
                vb += h0[k] * s_w1[k * 30 + 2 * i + 1];
            }
            hw[i] = pack2(fmaxf(va, 0.f), fmaxf(vb, 0.f));
        }
        hw[15] = pack2(1.0f, 0.f);
        uint4* hb = (uint4*)&s_h1b[t * 40];
        hb[0] = make_uint4(hw[0], hw[1], hw[2], hw[3]);
        hb[1] = make_uint4(hw[4], hw[5], hw[6], hw[7]);
        hb[2] = make_uint4(hw[8], hw[9], hw[10], hw[11]);
        hb[3] = make_uint4(hw[12], hw[13], hw[14], hw[15]);

        const float* xp = x1 + (size_t)src[eid] * C1;
        uint4* xb = (uint4*)&s_x1b[t * 40];
        #pragma unroll
        for (int q = 0; q < 4; ++q) {
            const float4 v0 = *(const float4*)(xp + q * 8);
            const float4 v1 = *(const float4*)(xp + q * 8 + 4);
            xb[q] = make_uint4(pack2(v0.x, v0.y), pack2(v0.z, v0.w),
                               pack2(v1.x, v1.y), pack2(v1.z, v1.w));
        }
    }
    __syncthreads();

    // ---- compute ----
    const int wv = t >> 6, lane = t & 63;
    const int n = lane & 15, quad = lane >> 4;
    const int e0 = wv * 64;

    float xf[4][8];
    #pragma unroll
    for (int m = 0; m < 4; ++m) {
        const uint4 xv = *(const uint4*)&s_x1b[(e0 + m * 16 + n) * 40 + quad * 8];
        xf[m][0] = __uint_as_float(xv.x << 16);
        xf[m][1] = __uint_as_float(xv.x & 0xFFFF0000u);
        xf[m][2] = __uint_as_float(xv.y << 16);
        xf[m][3] = __uint_as_float(xv.y & 0xFFFF0000u);
        xf[m][4] = __uint_as_float(xv.z << 16);
        xf[m][5] = __uint_as_float(xv.z & 0xFFFF0000u);
        xf[m][6] = __uint_as_float(xv.w << 16);
        xf[m][7] = __uint_as_float(xv.w & 0xFFFF0000u);
    }

    f32x4 acc[4][4];
    #pragma unroll
    for (int m = 0; m < 4; ++m)
        #pragma unroll
        for (int nt = 0; nt < 4; ++nt) acc[m][nt] = (f32x4){0.f, 0.f, 0.f, 0.f};

    #pragma unroll 4
    for (int kc = 0; kc < 32; ++kc) {
        bf16x8 bfr[4];
        #pragma unroll
        for (int nt = 0; nt < 4; ++nt)
            bfr[nt] = *(const bf16x8*)(wbt2 + (((kc * 4 + nt) * 16 + n) << 5) + quad * 8);
        #pragma unroll
        for (int m = 0; m < 4; ++m) {
            const unsigned hv = s_h1b[(e0 + m * 16 + n) * 40 + kc];
            const float hf = __uint_as_float(hv << 16);
            union { unsigned u[4]; bf16x8 v; } af;
            #pragma unroll
            for (int i = 0; i < 4; ++i)
                af.u[i] = pack2(hf * xf[m][2 * i], hf * xf[m][2 * i + 1]);
            #pragma unroll
            for (int nt = 0; nt < 4; ++nt)
                acc[m][nt] = __builtin_amdgcn_mfma_f32_16x16x32_bf16(af.v, bfr[nt], acc[m][nt], 0, 0, 0);
        }
    }

    #pragma unroll
    for (int m = 0; m < 4; ++m)
        #pragma unroll
        for (int r = 0; r < 4; ++r) {
            const int tb = tgt[tile + e0 + m * 16 + quad * 4 + r] * C2;
            #pragma unroll
            for (int nt = 0; nt < 4; ++nt)
                atomicAdd(&agg2[tb + nt * 16 + n], acc[m][nt][r]);
        }
}

// x2 = relu(agg2 + x1@root + bias);  xw = x2 @ W  — fused, x2 never stored.
__global__ __launch_bounds__(256) void nu2_xw(
    const float* __restrict__ x1, const float* __restrict__ agg2,
    const float* __restrict__ root, const float* __restrict__ bias,
    const float* __restrict__ W, float* __restrict__ xw)
{
    __shared__ float s_x1[256];
    __shared__ float s_x2[8 * 68];
    __shared__ float s_root[2048];
    __shared__ float s_W[2048];
    __shared__ float s_b[64];
    const int t = threadIdx.x;
    const int nb = blockIdx.x * 8;
    s_x1[t] = x1[nb * 32 + t];
    for (int i = t; i < 2048; i += 256) { s_root[i] = root[i]; s_W[i] = W[i]; }
    if (t < 64) s_b[t] = bias[t];
    __syncthreads();
    #pragma unroll
    for (int idx = t; idx < 512; idx += 256) {
        const int n2 = idx >> 6, c = idx & 63;
        float v = agg2[(nb + n2) * 64 + c] + s_b[c];
        #pragma unroll 8
        for (int k = 0; k < 32; ++k) v += s_x1[n2 * 32 + k] * s_root[k * 64 + c];
        s_x2[n2 * 68 + c] = fmaxf(v, 0.f);
    }
    __syncthreads();
    const int n2 = t >> 5, c3 = t & 31;
    float v = 0.f;
    #pragma unroll 8
    for (int k = 0; k < 64; ++k) v += s_x2[n2 * 68 + k] * s_W[k * 32 + c3];
    xw[(nb + n2) * 32 + c3] = v;
}

__global__ __launch_bounds__(256) void gcn_scatter(
    const float* __restrict__ xw, const int* __restrict__ gs,
    const int* __restrict__ gt, const float* __restrict__ gw,
    float* __restrict__ agg3)
{
    const int t = blockIdx.x * 256 + threadIdx.x;
    const int i = t >> 5, lane = t & 31;
    const float v = gw[i] * xw[gs[i] * C3 + lane];
    atomicAdd(&agg3[gt[i] * C3 + lane], v);
}

__global__ __launch_bounds__(256) void final_pool(
    const float* __restrict__ agg3, const float* __restrict__ gb,
    const int* __restrict__ seg, float* __restrict__ out)
{
    const int t = blockIdx.x * 256 + threadIdx.x;
    const int n = t >> 5, c = t & 31;
    const float v = fmaxf(agg3[t] + gb[c], 0.f);
    atomicAdd(&out[seg[n] * C3 + c], v);
}

extern "C" void kernel_launch(void* const* d_in, const int* in_sizes, int n_in,
                              void* d_out, int out_size, void* d_ws, size_t ws_size,
                              hipStream_t stream)
{
    const float* x       = (const float*)d_in[0];
    const float* e       = (const float*)d_in[1];
    const int*   src     = (const int*)d_in[2];
    const int*   tgt     = (const int*)d_in[3];
    const int*   seg     = (const int*)d_in[4];
    const int*   gcn_src = (const int*)d_in[5];
    const int*   gcn_tgt = (const int*)d_in[6];
    const float* gcn_w   = (const float*)d_in[7];
    const float* e1_w0   = (const float*)d_in[8];
    const float* e1_b0   = (const float*)d_in[9];
    const float* e1_w1   = (const float*)d_in[10];
    const float* e1_b1   = (const float*)d_in[11];
    const float* e1_wk   = (const float*)d_in[12];
    const float* e1_bk   = (const float*)d_in[13];
    const float* e1_root = (const float*)d_in[14];
    const float* e1_bias = (const float*)d_in[15];
    const float* e2_w0   = (const float*)d_in[16];
    const float* e2_b0   = (const float*)d_in[17];
    const float* e2_w1   = (const float*)d_in[18];
    const float* e2_b1   = (const float*)d_in[19];
    const float* e2_wk   = (const float*)d_in[20];
    const float* e2_bk   = (const float*)d_in[21];
    const float* e2_root = (const float*)d_in[22];
    const float* e2_bias = (const float*)d_in[23];
    const float* gcn_W   = (const float*)d_in[24];
    const float* gcn_b   = (const float*)d_in[25];
    float* out = (float*)d_out;

    float* ws   = (float*)d_ws;
    float* buf1 = ws;                                  // agg1 -> x1   [N, C1]
    float* buf2 = ws + N_NODES * C1;                   // agg2         [N, C2]
    float* buf3 = ws + N_NODES * (C1 + C2);            // agg3         [N, C3]
    float* bxw  = ws + N_NODES * (C1 + C2 + C3);       // xw           [N, C3]
    short* wbt2 = (short*)(ws + N_NODES * (C1 + C2 + C3 + C3));  // 65536 bf16
    short* wbt1 = wbt2 + 65536;                        // 8192 bf16

    // buf1..buf3 are contiguous: one memset
    hipMemsetAsync(buf1, 0, (size_t)N_NODES * (C1 + C2 + C3) * sizeof(float), stream);
    hipMemsetAsync(out, 0, (size_t)out_size * sizeof(float), stream);

    build_wbt<<<288, 256, 0, stream>>>(e2_wk, e2_bk, e1_wk, e1_bk, wbt2, wbt1);

    ecc1_mfma<<<E_EDGES / 256, 256, 0, stream>>>(x, e, src, tgt,
        e1_w0, e1_b0, e1_w1, e1_b1, wbt1, buf1);
    node_update1<<<(N_NODES * C1) / 256, 256, 0, stream>>>(x, e1_root, e1_bias, buf1);
    ecc2_mfma<<<E_EDGES / 256, 256, 0, stream>>>(buf1, e, src, tgt,
        e2_w0, e2_b0, e2_w1, e2_b1, wbt2, buf2);
    nu2_xw<<<N_NODES / 8, 256, 0, stream>>>(buf1, buf2, e2_root, e2_bias, gcn_W, bxw);
    gcn_scatter<<<((E_EDGES + N_NODES) * C3) / 256, 256, 0, stream>>>(
        bxw, gcn_src, gcn_tgt, gcn_w, buf3);
    final_pool<<<(N_NODES * C3) / 256, 256, 0, stream>>>(buf3, gcn_b, seg, out);
}

// Round 5
// 220.838 us; speedup vs baseline: 2.4542x; 1.0333x over previous
//
#include <hip/hip_runtime.h>
#include <hip/hip_bf16.h>

#define N_NODES 16384
#define E_EDGES 131072
#define F_IN 6
#define S_DIM 4
#define G_GRAPHS 256
#define H_DIM 30
#define C1 32
#define C2 64
#define C3 32

typedef __attribute__((ext_vector_type(8))) short bf16x8;
typedef __attribute__((ext_vector_type(4))) float f32x4;

__device__ __forceinline__ short f2bf(float f) {
    union { float f; unsigned u; } a; a.f = f;
    unsigned r = a.u + 0x7FFFu + ((a.u >> 16) & 1u);
    return (short)(r >> 16);
}

// pack two f32 -> (bf16(a) low16, bf16(b) high16), 3 VALU ops
__device__ __forceinline__ unsigned pack2(float a, float b) {
    unsigned ua = __float_as_uint(a) + 0x8000u;
    unsigned ub = __float_as_uint(b) + 0x8000u;
    return __builtin_amdgcn_perm(ub, ua, 0x07060302u);
}

// ---------------------------------------------------------------------------
// Weight builder (same layout as R4).
// wbt2[kc 32][nt 4][n 16][kq 4][j 8] = W2'[K=kc*32+kq*8+j][c2=nt*16+n]
// wbt1[kc 8][nt 2][n 16][kq 4][j 8], h=kc*4+kq, f=j(<6), c1=nt*16+n
// ---------------------------------------------------------------------------
__global__ __launch_bounds__(256) void build_wbt(
    const float* __restrict__ wk2, const float* __restrict__ bk2,
    const float* __restrict__ wk1, const float* __restrict__ bk1,
    short* __restrict__ wbt2, short* __restrict__ wbt1)
{
    const int idx = blockIdx.x * 256 + threadIdx.x;
    if (idx < 65536) {
        const int j = idx & 7, kq = (idx >> 3) & 3, n = (idx >> 5) & 15;
        const int nt = (idx >> 9) & 3, kc = idx >> 11;
        const int c1 = kq * 8 + j, c2 = nt * 16 + n;
        float v = (kc < 30) ? wk2[kc * 2048 + c1 * 64 + c2]
                            : ((kc == 30) ? bk2[c1 * 64 + c2] : 0.f);
        wbt2[idx] = f2bf(v);
    } else {
        const int i2 = idx - 65536;
        const int j = i2 & 7, kq = (i2 >> 3) & 3, n = (i2 >> 5) & 15;
        const int nt = (i2 >> 9) & 1, kc = i2 >> 10;
        const int h = kc * 4 + kq, c1 = nt * 16 + n;
        float v = 0.f;
        if (j < 6) {
            if (h < 30) v = wk1[h * 192 + j * 32 + c1];
            else if (h == 30) v = bk1[j * 32 + c1];
        }
        wbt1[i2] = f2bf(v);
    }
}

// ---------------------------------------------------------------------------
// CSR build over tgt (shared by ECC1/ECC2/GCN gathers).
// ---------------------------------------------------------------------------
__global__ __launch_bounds__(256) void csr_hist(
    const int* __restrict__ tgt, int* __restrict__ deg)
{
    const int i = blockIdx.x * 256 + threadIdx.x;
    atomicAdd(&deg[tgt[i]], 1);
}

// single block, 1024 threads, 16 elems/thread exclusive scan over N=16384
__global__ __launch_bounds__(1024) void csr_scan(
    const int* __restrict__ deg, int* __restrict__ off, int* __restrict__ cursor)
{
    __shared__ int s[1024];
    const int t = threadIdx.x;
    const int base = t * 16;
    int loc[16]; int sum = 0;
    #pragma unroll
    for (int i = 0; i < 16; ++i) { loc[i] = sum; sum += deg[base + i]; }
    s[t] = sum;
    __syncthreads();
    int v = sum;
    for (int d = 1; d < 1024; d <<= 1) {
        const int add = (t >= d) ? s[t - d] : 0;
        __syncthreads();
        v += add; s[t] = v;
        __syncthreads();
    }
    const int pre = v - sum;
    #pragma unroll
    for (int i = 0; i < 16; ++i) {
        const int o = pre + loc[i];
        off[base + i] = o; cursor[base + i] = o;
    }
    if (t == 1023) off[N_NODES] = pre + sum;
}

__global__ __launch_bounds__(256) void csr_permute(
    const int* __restrict__ tgt, int* __restrict__ cursor, int* __restrict__ eidx)
{
    const int e = blockIdx.x * 256 + threadIdx.x;
    const int p = atomicAdd(&cursor[tgt[e]], 1);
    eidx[p] = e;
}

// ---------------------------------------------------------------------------
// ECC1: outer-product GEMM, msg stored as packed bf16 (no atomics).
// msg1[edge*16 + n] = pack(col n, col 16+n)
// ---------------------------------------------------------------------------
__global__ __launch_bounds__(256, 2) void ecc1_mfma(
    const float* __restrict__ x, const float* __restrict__ e,
    const int* __restrict__ src,
    const float* __restrict__ w0, const float* __restrict__ b0,
    const float* __restrict__ w1, const float* __restrict__ b1,
    const short* __restrict__ wbt1, unsigned* __restrict__ msg1)
{
    __shared__ unsigned short s_h1b[256 * 40];
    __shared__ unsigned short s_xb[256 * 8];
    __shared__ float s_w0[120], s_b0[30], s_w1[900], s_b1[30];

    const int t = threadIdx.x;
    const int tile = blockIdx.x * 256;
    for (int i = t; i < 120; i += 256) s_w0[i] = w0[i];
    for (int i = t; i < 900; i += 256) s_w1[i] = w1[i];
    if (t < 30) { s_b0[t] = b0[t]; s_b1[t] = b1[t]; }
    __syncthreads();

    // ---- phase A: per-thread edge MLP + x staging ----
    {
        const int eid = tile + t;
        const float4 ev = *(const float4*)(e + eid * 4);
        float h0[30];
        #pragma unroll
        for (int j = 0; j < 30; ++j) {
            float v = ev.x * s_w0[j] + ev.y * s_w0[30 + j]
                    + ev.z * s_w0[60 + j] + ev.w * s_w0[90 + j] + s_b0[j];
            h0[j] = fmaxf(v, 0.f);
        }
        unsigned hw[16];
        #pragma unroll
        for (int i = 0; i < 15; ++i) {
            float va = s_b1[2 * i], vb = s_b1[2 * i + 1];
            #pragma unroll
            for (int k = 0; k < 30; ++k) {
                va += h0[k] * s_w1[k * 30 + 2 * i];
                vb += h0[k] * s_w1[k * 30 + 2 * i + 1];
            }
            hw[i] = pack2(fmaxf(va, 0.f), fmaxf(vb, 0.f));
        }
        hw[15] = pack2(1.0f, 0.f);
        uint4* hb = (uint4*)&s_h1b[t * 40];
        hb[0] = make_uint4(hw[0], hw[1], hw[2], hw[3]);
        hb[1] = make_uint4(hw[4], hw[5], hw[6], hw[7]);
        hb[2] = make_uint4(hw[8], hw[9], hw[10], hw[11]);
        hb[3] = make_uint4(hw[12], hw[13], hw[14], hw[15]);

        const float2* xp = (const float2*)(x + (size_t)src[eid] * F_IN);
        const float2 a = xp[0], b = xp[1], c = xp[2];
        *(uint4*)&s_xb[t * 8] =
            make_uint4(pack2(a.x, a.y), pack2(b.x, b.y), pack2(c.x, c.y), 0u);
    }
    __syncthreads();

    const int wv = t >> 6, lane = t & 63;
    const int n = lane & 15, quad = lane >> 4;
    const int e0 = wv * 64;

    float xf[4][8];
    #pragma unroll
    for (int m = 0; m < 4; ++m) {
        const uint4 xv = *(const uint4*)&s_xb[(e0 + m * 16 + n) * 8];
        xf[m][0] = __uint_as_float(xv.x << 16);
        xf[m][1] = __uint_as_float(xv.x & 0xFFFF0000u);
        xf[m][2] = __uint_as_float(xv.y << 16);
        xf[m][3] = __uint_as_float(xv.y & 0xFFFF0000u);
        xf[m][4] = __uint_as_float(xv.z << 16);
        xf[m][5] = __uint_as_float(xv.z & 0xFFFF0000u);
        xf[m][6] = 0.f; xf[m][7] = 0.f;
    }

    f32x4 acc[4][2];
    #pragma unroll
    for (int m = 0; m < 4; ++m)
        #pragma unroll
        for (int nt = 0; nt < 2; ++nt) acc[m][nt] = (f32x4){0.f, 0.f, 0.f, 0.f};

    #pragma unroll
    for (int kc = 0; kc < 8; ++kc) {
        bf16x8 bfr[2];
        #pragma unroll
        for (int nt = 0; nt < 2; ++nt)
            bfr[nt] = *(const bf16x8*)(wbt1 + (((kc * 2 + nt) * 16 + n) << 5) + quad * 8);
        #pragma unroll
        for (int m = 0; m < 4; ++m) {
            const unsigned hv = s_h1b[(e0 + m * 16 + n) * 40 + kc * 4 + quad];
            const float hf = __uint_as_float(hv << 16);
            union { unsigned u[4]; bf16x8 v; } af;
            #pragma unroll
            for (int i = 0; i < 4; ++i)
                af.u[i] = pack2(hf * xf[m][2 * i], hf * xf[m][2 * i + 1]);
            acc[m][0] = __builtin_amdgcn_mfma_f32_16x16x32_bf16(af.v, bfr[0], acc[m][0], 0, 0, 0);
            acc[m][1] = __builtin_amdgcn_mfma_f32_16x16x32_bf16(af.v, bfr[1], acc[m][1], 0, 0, 0);
        }
    }

    #pragma unroll
    for (int m = 0; m < 4; ++m)
        #pragma unroll
        for (int r = 0; r < 4; ++r) {
            const int edge = tile + e0 + m * 16 + quad * 4 + r;
            msg1[edge * 16 + n] = pack2(acc[m][0][r], acc[m][1][r]);
        }
}

// gather msg1 over CSR + fused node update 1 -> x1
__global__ __launch_bounds__(256) void gather1(
    const unsigned* __restrict__ msg1, const int* __restrict__ off,
    const int* __restrict__ eidx, const float* __restrict__ x,
    const float* __restrict__ root, const float* __restrict__ bias,
    float* __restrict__ x1)
{
    __shared__ float s_root[192];
    __shared__ float s_b[32];
    const int t = threadIdx.x;
    if (t < 192) s_root[t] = root[t];
    if (t < 32) s_b[t] = bias[t];
    __syncthreads();
    const int v = blockIdx.x * 16 + (t >> 4);
    const int n = t & 15;
    const int o0 = off[v], o1 = off[v + 1];
    float sa = 0.f, sb = 0.f;
    for (int j = o0; j < o1; ++j) {
        const unsigned u = msg1[eidx[j] * 16 + n];
        sa += __uint_as_float(u << 16);
        sb += __uint_as_float(u & 0xFFFF0000u);
    }
    const float* xr = x + (size_t)v * F_IN;
    float ra = s_b[n], rb = s_b[16 + n];
    #pragma unroll
    for (int f = 0; f < 6; ++f) {
        const float xv = xr[f];
        ra += xv * s_root[f * 32 + n];
        rb += xv * s_root[f * 32 + 16 + n];
    }
    x1[v * 32 + n] = fmaxf(sa + ra, 0.f);
    x1[v * 32 + 16 + n] = fmaxf(sb + rb, 0.f);
}

// ---------------------------------------------------------------------------
// ECC2: outer-product GEMM, msg stored as packed bf16 pairs (no atomics).
// msg2[edge*32 + n*2 + p]: p=0 -> (col n, col 16+n), p=1 -> (col 32+n, 48+n)
// ---------------------------------------------------------------------------
__global__ __launch_bounds__(256, 2) void ecc2_mfma(
    const float* __restrict__ x1, const float* __restrict__ e,
    const int* __restrict__ src,
    const float* __restrict__ w0, const float* __restrict__ b0,
    const float* __restrict__ w1, const float* __restrict__ b1,
    const short* __restrict__ wbt2, unsigned* __restrict__ msg2)
{
    __shared__ unsigned short s_h1b[256 * 40];
    __shared__ unsigned short s_x1b[256 * 40];
    __shared__ float s_w0[120], s_b0[30], s_w1[900], s_b1[30];

    const int t = threadIdx.x;
    const int tile = blockIdx.x * 256;
    for (int i = t; i < 120; i += 256) s_w0[i] = w0[i];
    for (int i = t; i < 900; i += 256) s_w1[i] = w1[i];
    if (t < 30) { s_b0[t] = b0[t]; s_b1[t] = b1[t]; }
    __syncthreads();

    // ---- phase A ----
    {
        const int eid = tile + t;
        const float4 ev = *(const float4*)(e + eid * 4);
        float h0[30];
        #pragma unroll
        for (int j = 0; j < 30; ++j) {
            float v = ev.x * s_w0[j] + ev.y * s_w0[30 + j]
                    + ev.z * s_w0[60 + j] + ev.w * s_w0[90 + j] + s_b0[j];
            h0[j] = fmaxf(v, 0.f);
        }
        unsigned hw[16];
        #pragma unroll
        for (int i = 0; i < 15; ++i) {
            float va = s_b1[2 * i], vb = s_b1[2 * i + 1];
            #pragma unroll
            for (int k = 0; k < 30; ++k) {
                va += h0[k] * s_w1[k * 30 + 2 * i];
                vb += h0[k] * s_w1[k * 30 + 2 * i + 1];
            }
            hw[i] = pack2(fmaxf(va, 0.f), fmaxf(vb, 0.f));
        }
        hw[15] = pack2(1.0f, 0.f);
        uint4* hb = (uint4*)&s_h1b[t * 40];
        hb[0] = make_uint4(hw[0], hw[1], hw[2], hw[3]);
        hb[1] = make_uint4(hw[4], hw[5], hw[6], hw[7]);
        hb[2] = make_uint4(hw[8], hw[9], hw[10], hw[11]);
        hb[3] = make_uint4(hw[12], hw[13], hw[14], hw[15]);

        const float* xp = x1 + (size_t)src[eid] * C1;
        uint4* xb = (uint4*)&s_x1b[t * 40];
        #pragma unroll
        for (int q = 0; q < 4; ++q) {
            const float4 v0 = *(const float4*)(xp + q * 8);
            const float4 v1 = *(const float4*)(xp + q * 8 + 4);
            xb[q] = make_uint4(pack2(v0.x, v0.y), pack2(v0.z, v0.w),
                               pack2(v1.x, v1.y), pack2(v1.z, v1.w));
        }
    }
    __syncthreads();

    const int wv = t >> 6, lane = t & 63;
    const int n = lane & 15, quad = lane >> 4;
    const int e0 = wv * 64;

    float xf[4][8];
    #pragma unroll
    for (int m = 0; m < 4; ++m) {
        const uint4 xv = *(const uint4*)&s_x1b[(e0 + m * 16 + n) * 40 + quad * 8];
        xf[m][0] = __uint_as_float(xv.x << 16);
        xf[m][1] = __uint_as_float(xv.x & 0xFFFF0000u);
        xf[m][2] = __uint_as_float(xv.y << 16);
        xf[m][3] = __uint_as_float(xv.y & 0xFFFF0000u);
        xf[m][4] = __uint_as_float(xv.z << 16);
        xf[m][5] = __uint_as_float(xv.z & 0xFFFF0000u);
        xf[m][6] = __uint_as_float(xv.w << 16);
        xf[m][7] = __uint_as_float(xv.w & 0xFFFF0000u);
    }

    f32x4 acc[4][4];
    #pragma unroll
    for (int m = 0; m < 4; ++m)
        #pragma unroll
        for (int nt = 0; nt < 4; ++nt) acc[m][nt] = (f32x4){0.f, 0.f, 0.f, 0.f};

    #pragma unroll 4
    for (int kc = 0; kc < 32; ++kc) {
        bf16x8 bfr[4];
        #pragma unroll
        for (int nt = 0; nt < 4; ++nt)
            bfr[nt] = *(const bf16x8*)(wbt2 + (((kc * 4 + nt) * 16 + n) << 5) + quad * 8);
        #pragma unroll
        for (int m = 0; m < 4; ++m) {
            const unsigned hv = s_h1b[(e0 + m * 16 + n) * 40 + kc];
            const float hf = __uint_as_float(hv << 16);
            union { unsigned u[4]; bf16x8 v; } af;
            #pragma unroll
            for (int i = 0; i < 4; ++i)
                af.u[i] = pack2(hf * xf[m][2 * i], hf * xf[m][2 * i + 1]);
            #pragma unroll
            for (int nt = 0; nt < 4; ++nt)
                acc[m][nt] = __builtin_amdgcn_mfma_f32_16x16x32_bf16(af.v, bfr[nt], acc[m][nt], 0, 0, 0);
        }
    }

    #pragma unroll
    for (int m = 0; m < 4; ++m)
        #pragma unroll
        for (int r = 0; r < 4; ++r) {
            const int edge = tile + e0 + m * 16 + quad * 4 + r;
            uint2 val;
            val.x = pack2(acc[m][0][r], acc[m][1][r]);
            val.y = pack2(acc[m][2][r], acc[m][3][r]);
            *(uint2*)&msg2[edge * 32 + n * 2] = val;
        }
}

// gather msg2 + fused node update 2 + xw = x2 @ gcn_W  -> xw
__global__ __launch_bounds__(256) void gather2(
    const unsigned* __restrict__ msg2, const int* __restrict__ off,
    const int* __restrict__ eidx, const float* __restrict__ x1,
    const float* __restrict__ root, const float* __restrict__ bias,
    const float* __restrict__ W, float* __restrict__ xw)
{
    __shared__ float s_root[2048], s_W[2048], s_b[64];
    __shared__ float s_x2[8][68];
    __shared__ float s_x1v[256];
    const int t = threadIdx.x;
    for (int i = t; i < 2048; i += 256) { s_root[i] = root[i]; s_W[i] = W[i]; }
    if (t < 64) s_b[t] = bias[t];
    s_x1v[t] = x1[blockIdx.x * 256 + t];
    __syncthreads();

    const int lv = t >> 5;
    const int v = blockIdx.x * 8 + lv;
    const int j5 = t & 31;
    const int n = j5 >> 1, p = j5 & 1;
    const int ca = p * 32 + n, cb = p * 32 + 16 + n;
    const int o0 = off[v], o1 = off[v + 1];
    float sa = 0.f, sb = 0.f;
    for (int j = o0; j < o1; ++j) {
        const unsigned u = msg2[eidx[j] * 32 + j5];
        sa += __uint_as_float(u << 16);
        sb += __uint_as_float(u & 0xFFFF0000u);
    }
    float ra = s_b[ca], rb = s_b[cb];
    #pragma unroll 8
    for (int k = 0; k < 32; ++k) {
        const float xv = s_x1v[lv * 32 + k];
        ra += xv * s_root[k * 64 + ca];
        rb += xv * s_root[k * 64 + cb];
    }
    s_x2[lv][ca] = fmaxf(sa + ra, 0.f);
    s_x2[lv][cb] = fmaxf(sb + rb, 0.f);
    __syncthreads();

    float acc = 0.f;
    #pragma unroll 8
    for (int k = 0; k < 64; ++k) acc += s_x2[lv][k] * s_W[k * 32 + j5];
    xw[v * 32 + j5] = acc;
}

// GCN gather (weighted, + self loop) + relu + global pool (atomics on [G,C3])
__global__ __launch_bounds__(256) void gcn_pool(
    const float* __restrict__ xw, const int* __restrict__ off,
    const int* __restrict__ eidx, const int* __restrict__ src,
    const float* __restrict__ gw, const float* __restrict__ gb,
    const int* __restrict__ seg, float* __restrict__ out)
{
    __shared__ float s_gb[32];
    const int t = threadIdx.x;
    if (t < 32) s_gb[t] = gb[t];
    __syncthreads();
    const int v = blockIdx.x * 8 + (t >> 5);
    const int c = t & 31;
    const int o0 = off[v], o1 = off[v + 1];
    float s = gw[E_EDGES + v] * xw[v * 32 + c];   // self loop
    for (int j = o0; j < o1; ++j) {
        const int e = eidx[j];
        s += gw[e] * xw[src[e] * 32 + c];
    }
    const float val = fmaxf(s + s_gb[c], 0.f);
    atomicAdd(&out[seg[v] * 32 + c], val);
}

extern "C" void kernel_launch(void* const* d_in, const int* in_sizes, int n_in,
                              void* d_out, int out_size, void* d_ws, size_t ws_size,
                              hipStream_t stream)
{
    const float* x       = (const float*)d_in[0];
    const float* e       = (const float*)d_in[1];
    const int*   src     = (const int*)d_in[2];
    const int*   tgt     = (const int*)d_in[3];
    const int*   seg     = (const int*)d_in[4];
    const float* gcn_w   = (const float*)d_in[7];
    const float* e1_w0   = (const float*)d_in[8];
    const float* e1_b0   = (const float*)d_in[9];
    const float* e1_w1   = (const float*)d_in[10];
    const float* e1_b1   = (const float*)d_in[11];
    const float* e1_wk   = (const float*)d_in[12];
    const float* e1_bk   = (const float*)d_in[13];
    const float* e1_root = (const float*)d_in[14];
    const float* e1_bias = (const float*)d_in[15];
    const float* e2_w0   = (const float*)d_in[16];
    const float* e2_b0   = (const float*)d_in[17];
    const float* e2_w1   = (const float*)d_in[18];
    const float* e2_b1   = (const float*)d_in[19];
    const float* e2_wk   = (const float*)d_in[20];
    const float* e2_bk   = (const float*)d_in[21];
    const float* e2_root = (const float*)d_in[22];
    const float* e2_bias = (const float*)d_in[23];
    const float* gcn_W   = (const float*)d_in[24];
    const float* gcn_b   = (const float*)d_in[25];
    float* out = (float*)d_out;

    float*    ws    = (float*)d_ws;
    float*    x1    = ws;                                   // [N,32] f32
    float*    xw    = x1 + (size_t)N_NODES * 32;            // [N,32] f32
    unsigned* msg1  = (unsigned*)(xw + (size_t)N_NODES * 32);   // E*16 dwords
    unsigned* msg2  = msg1 + (size_t)E_EDGES * 16;          // E*32 dwords
    short*    wbt2  = (short*)(msg2 + (size_t)E_EDGES * 32);// 65536 bf16
    short*    wbt1  = wbt2 + 65536;                         // 8192 bf16
    int*      deg   = (int*)(wbt1 + 8192);                  // N
    int*      off   = deg + N_NODES;                        // N+1 (pad 16)
    int*      cursor= off + N_NODES + 16;                   // N
    int*      eidx  = cursor + N_NODES;                     // E

    hipMemsetAsync(deg, 0, N_NODES * sizeof(int), stream);
    hipMemsetAsync(out, 0, (size_t)out_size * sizeof(float), stream);

    build_wbt<<<288, 256, 0, stream>>>(e2_wk, e2_bk, e1_wk, e1_bk, wbt2, wbt1);
    csr_hist<<<E_EDGES / 256, 256, 0, stream>>>(tgt, deg);
    csr_scan<<<1, 1024, 0, stream>>>(deg, off, cursor);
    csr_permute<<<E_EDGES / 256, 256, 0, stream>>>(tgt, cursor, eidx);

    ecc1_mfma<<<E_EDGES / 256, 256, 0, stream>>>(x, e, src,
        e1_w0, e1_b0, e1_w1, e1_b1, wbt1, msg1);
    gather1<<<N_NODES / 16, 256, 0, stream>>>(msg1, off, eidx, x,
        e1_root, e1_bias, x1);
    ecc2_mfma<<<E_EDGES / 256, 256, 0, stream>>>(x1, e, src,
        e2_w0, e2_b0, e2_w1, e2_b1, wbt2, msg2);
    gather2<<<N_NODES / 8, 256, 0, stream>>>(msg2, off, eidx, x1,
        e2_root, e2_bias, gcn_W, xw);
    gcn_pool<<<N_NODES / 8, 256, 0, stream>>>(xw, off, eidx, src,
        gcn_w, gcn_b, seg, out);
}

// Round 7
// 209.984 us; speedup vs baseline: 2.5811x; 1.0517x over previous
//
#include <hip/hip_runtime.h>
#include <hip/hip_bf16.h>

#define N_NODES 16384
#define E_EDGES 131072
#define F_IN 6
#define S_DIM 4
#define G_GRAPHS 256
#define H_DIM 30
#define C1 32
#define C2 64
#define C3 32

typedef __attribute__((ext_vector_type(8))) short bf16x8;
typedef __attribute__((ext_vector_type(4))) float f32x4;

__device__ __forceinline__ short f2bf(float f) {
    union { float f; unsigned u; } a; a.f = f;
    unsigned r = a.u + 0x7FFFu + ((a.u >> 16) & 1u);
    return (short)(r >> 16);
}

// pack two f32 -> (bf16(a) low16, bf16(b) high16)
__device__ __forceinline__ unsigned pack2(float a, float b) {
    unsigned ua = __float_as_uint(a) + 0x8000u;
    unsigned ub = __float_as_uint(b) + 0x8000u;
    return __builtin_amdgcn_perm(ub, ua, 0x07060302u);
}

// ---------------------------------------------------------------------------
// prep: build wbt1/wbt2 + degree histogram (deg pre-zeroed by memset).
// grid = E/256 = 512 blocks.
// ---------------------------------------------------------------------------
__global__ __launch_bounds__(256) void prep(
    const float* __restrict__ wk2, const float* __restrict__ bk2,
    const float* __restrict__ wk1, const float* __restrict__ bk1,
    const int* __restrict__ tgt,
    short* __restrict__ wbt2, short* __restrict__ wbt1,
    int* __restrict__ deg)
{
    const int gtid = blockIdx.x * 256 + threadIdx.x;
    if (gtid < 65536) {
        const int idx = gtid;
        const int j = idx & 7, kq = (idx >> 3) & 3, n = (idx >> 5) & 15;
        const int nt = (idx >> 9) & 3, kc = idx >> 11;
        const int c1 = kq * 8 + j, c2 = nt * 16 + n;
        float v = (kc < 30) ? wk2[kc * 2048 + c1 * 64 + c2]
                            : ((kc == 30) ? bk2[c1 * 64 + c2] : 0.f);
        wbt2[idx] = f2bf(v);
    } else if (gtid < 73728) {
        const int i2 = gtid - 65536;
        const int j = i2 & 7, kq = (i2 >> 3) & 3, n = (i2 >> 5) & 15;
        const int nt = (i2 >> 9) & 1, kc = i2 >> 10;
        const int h = kc * 4 + kq, c1 = nt * 16 + n;
        float v = 0.f;
        if (j < 6) {
            if (h < 30) v = wk1[h * 192 + j * 32 + c1];
            else if (h == 30) v = bk1[j * 32 + c1];
        }
        wbt1[i2] = f2bf(v);
    }
    atomicAdd(&deg[tgt[gtid]], 1);
}

// single block, 1024 threads, 16 elems/thread exclusive scan over N=16384
__global__ __launch_bounds__(1024) void csr_scan(
    const int* __restrict__ deg, int* __restrict__ off, int* __restrict__ cursor)
{
    __shared__ int s[1024];
    const int t = threadIdx.x;
    const int base = t * 16;
    int loc[16]; int sum = 0;
    #pragma unroll
    for (int i = 0; i < 16; ++i) { loc[i] = sum; sum += deg[base + i]; }
    s[t] = sum;
    __syncthreads();
    int v = sum;
    for (int d = 1; d < 1024; d <<= 1) {
        const int add = (t >= d) ? s[t - d] : 0;
        __syncthreads();
        v += add; s[t] = v;
        __syncthreads();
    }
    const int pre = v - sum;
    #pragma unroll
    for (int i = 0; i < 16; ++i) {
        const int o = pre + loc[i];
        off[base + i] = o; cursor[base + i] = o;
    }
    if (t == 1023) off[N_NODES] = E_EDGES;
}

// ---------------------------------------------------------------------------
// ECC1 + fused CSR permute. Messages written at PERMUTED slot -> gathers
// become sequential. Also emits perm[e] (for ecc2) and CSR-ordered
// srcp/gwp (for gcn_pool).
// ---------------------------------------------------------------------------
__global__ __launch_bounds__(256, 2) void ecc1_mfma(
    const float* __restrict__ x, const float* __restrict__ e,
    const int* __restrict__ src, const int* __restrict__ tgt,
    const float* __restrict__ gcn_w,
    const float* __restrict__ w0, const float* __restrict__ b0,
    const float* __restrict__ w1, const float* __restrict__ b1,
    const short* __restrict__ wbt1,
    int* __restrict__ cursor, int* __restrict__ perm,
    int* __restrict__ srcp, float* __restrict__ gwp,
    unsigned* __restrict__ msg1)
{
    __shared__ unsigned short s_h1b[256 * 40];
    __shared__ unsigned short s_xb[256 * 8];
    __shared__ int s_perm[256];
    __shared__ float s_w0[120], s_b0[30], s_w1[900], s_b1[30];

    const int t = threadIdx.x;
    const int tile = blockIdx.x * 256;
    for (int i = t; i < 120; i += 256) s_w0[i] = w0[i];
    for (int i = t; i < 900; i += 256) s_w1[i] = w1[i];
    if (t < 30) { s_b0[t] = b0[t]; s_b1[t] = b1[t]; }
    __syncthreads();

    // ---- phase A: CSR permute + per-thread edge MLP + x staging ----
    {
        const int eid = tile + t;
        const int sv = src[eid];
        const int p = atomicAdd(&cursor[tgt[eid]], 1);
        s_perm[t] = p;
        perm[eid] = p;
        srcp[p] = sv;
        gwp[p] = gcn_w[eid];

        const float4 ev = *(const float4*)(e + eid * 4);
        float h0[30];
        #pragma unroll
        for (int j = 0; j < 30; ++j) {
            float v = ev.x * s_w0[j] + ev.y * s_w0[30 + j]
                    + ev.z * s_w0[60 + j] + ev.w * s_w0[90 + j] + s_b0[j];
            h0[j] = fmaxf(v, 0.f);
        }
        unsigned hw[16];
        #pragma unroll
        for (int i = 0; i < 15; ++i) {
            float va = s_b1[2 * i], vb = s_b1[2 * i + 1];
            #pragma unroll
            for (int k = 0; k < 30; ++k) {
                va += h0[k] * s_w1[k * 30 + 2 * i];
                vb += h0[k] * s_w1[k * 30 + 2 * i + 1];
            }
            hw[i] = pack2(fmaxf(va, 0.f), fmaxf(vb, 0.f));
        }
        hw[15] = pack2(1.0f, 0.f);
        uint4* hb = (uint4*)&s_h1b[t * 40];
        hb[0] = make_uint4(hw[0], hw[1], hw[2], hw[3]);
        hb[1] = make_uint4(hw[4], hw[5], hw[6], hw[7]);
        hb[2] = make_uint4(hw[8], hw[9], hw[10], hw[11]);
        hb[3] = make_uint4(hw[12], hw[13], hw[14], hw[15]);

        const float2* xp = (const float2*)(x + (size_t)sv * F_IN);
        const float2 a = xp[0], b2 = xp[1], c2 = xp[2];
        *(uint4*)&s_xb[t * 8] =
            make_uint4(pack2(a.x, a.y), pack2(b2.x, b2.y), pack2(c2.x, c2.y), 0u);
    }
    __syncthreads();

    const int wv = t >> 6, lane = t & 63;
    const int n = lane & 15, quad = lane >> 4;
    const int e0 = wv * 64;

    float xf[4][8];
    #pragma unroll
    for (int m = 0; m < 4; ++m) {
        const uint4 xv = *(const uint4*)&s_xb[(e0 + m * 16 + n) * 8];
        xf[m][0] = __uint_as_float(xv.x << 16);
        xf[m][1] = __uint_as_float(xv.x & 0xFFFF0000u);
        xf[m][2] = __uint_as_float(xv.y << 16);
        xf[m][3] = __uint_as_float(xv.y & 0xFFFF0000u);
        xf[m][4] = __uint_as_float(xv.z << 16);
        xf[m][5] = __uint_as_float(xv.z & 0xFFFF0000u);
        xf[m][6] = 0.f; xf[m][7] = 0.f;
    }

    f32x4 acc[4][2];
    #pragma unroll
    for (int m = 0; m < 4; ++m) {
        acc[m][0] = (f32x4){0.f, 0.f, 0.f, 0.f};
        acc[m][1] = (f32x4){0.f, 0.f, 0.f, 0.f};
    }

    #pragma unroll
    for (int kc = 0; kc < 8; ++kc) {
        bf16x8 bfr[2];
        #pragma unroll
        for (int nt = 0; nt < 2; ++nt)
            bfr[nt] = *(const bf16x8*)(wbt1 + (((kc * 2 + nt) * 16 + n) << 5) + quad * 8);
        #pragma unroll
        for (int m = 0; m < 4; ++m) {
            const unsigned hv = s_h1b[(e0 + m * 16 + n) * 40 + kc * 4 + quad];
            const float hf = __uint_as_float(hv << 16);
            union { unsigned u[4]; bf16x8 v; } af;
            #pragma unroll
            for (int i = 0; i < 4; ++i)
                af.u[i] = pack2(hf * xf[m][2 * i], hf * xf[m][2 * i + 1]);
            acc[m][0] = __builtin_amdgcn_mfma_f32_16x16x32_bf16(af.v, bfr[0], acc[m][0], 0, 0, 0);
            acc[m][1] = __builtin_amdgcn_mfma_f32_16x16x32_bf16(af.v, bfr[1], acc[m][1], 0, 0, 0);
        }
    }

    #pragma unroll
    for (int m = 0; m < 4; ++m)
        #pragma unroll
        for (int r = 0; r < 4; ++r) {
            const int p = s_perm[e0 + m * 16 + quad * 4 + r];
            msg1[p * 16 + n] = pack2(acc[m][0][r], acc[m][1][r]);
        }
}

// gather msg1 (SEQUENTIAL, permuted layout) + node update 1 -> x1
__global__ __launch_bounds__(256) void gather1(
    const unsigned* __restrict__ msg1, const int* __restrict__ off,
    const float* __restrict__ x,
    const float* __restrict__ root, const float* __restrict__ bias,
    float* __restrict__ x1)
{
    __shared__ float s_root[192];
    __shared__ float s_b[32];
    const int t = threadIdx.x;
    if (t < 192) s_root[t] = root[t];
    if (t < 32) s_b[t] = bias[t];
    __syncthreads();
    const int v = blockIdx.x * 16 + (t >> 4);
    const int n = t & 15;
    const int o0 = off[v], o1 = off[v + 1];
    float sa = 0.f, sb = 0.f;
    for (int j = o0; j < o1; ++j) {
        const unsigned u = msg1[j * 16 + n];
        sa += __uint_as_float(u << 16);
        sb += __uint_as_float(u & 0xFFFF0000u);
    }
    const float* xr = x + (size_t)v * F_IN;
    float ra = s_b[n], rb = s_b[16 + n];
    #pragma unroll
    for (int f = 0; f < 6; ++f) {
        const float xv = xr[f];
        ra += xv * s_root[f * 32 + n];
        rb += xv * s_root[f * 32 + 16 + n];
    }
    x1[v * 32 + n] = fmaxf(sa + ra, 0.f);
    x1[v * 32 + 16 + n] = fmaxf(sb + rb, 0.f);
}

// ---------------------------------------------------------------------------
// ECC2: outer-product MFMA, messages written at permuted slot.
// ---------------------------------------------------------------------------
__global__ __launch_bounds__(256, 2) void ecc2_mfma(
    const float* __restrict__ x1, const float* __restrict__ e,
    const int* __restrict__ src, const int* __restrict__ perm,
    const float* __restrict__ w0, const float* __restrict__ b0,
    const float* __restrict__ w1, const float* __restrict__ b1,
    const short* __restrict__ wbt2, unsigned* __restrict__ msg2)
{
    __shared__ unsigned short s_h1b[256 * 40];
    __shared__ unsigned short s_x1b[256 * 40];
    __shared__ int s_perm[256];
    __shared__ float s_w0[120], s_b0[30], s_w1[900], s_b1[30];

    const int t = threadIdx.x;
    const int tile = blockIdx.x * 256;
    for (int i = t; i < 120; i += 256) s_w0[i] = w0[i];
    for (int i = t; i < 900; i += 256) s_w1[i] = w1[i];
    if (t < 30) { s_b0[t] = b0[t]; s_b1[t] = b1[t]; }
    __syncthreads();

    // ---- phase A ----
    {
        const int eid = tile + t;
        s_perm[t] = perm[eid];
        const float4 ev = *(const float4*)(e + eid * 4);
        float h0[30];
        #pragma unroll
        for (int j = 0; j < 30; ++j) {
            float v = ev.x * s_w0[j] + ev.y * s_w0[30 + j]
                    + ev.z * s_w0[60 + j] + ev.w * s_w0[90 + j] + s_b0[j];
            h0[j] = fmaxf(v, 0.f);
        }
        unsigned hw[16];
        #pragma unroll
        for (int i = 0; i < 15; ++i) {
            float va = s_b1[2 * i], vb = s_b1[2 * i + 1];
            #pragma unroll
            for (int k = 0; k < 30; ++k) {
                va += h0[k] * s_w1[k * 30 + 2 * i];
                vb += h0[k] * s_w1[k * 30 + 2 * i + 1];
            }
            hw[i] = pack2(fmaxf(va, 0.f), fmaxf(vb, 0.f));
        }
        hw[15] = pack2(1.0f, 0.f);
        uint4* hb = (uint4*)&s_h1b[t * 40];
        hb[0] = make_uint4(hw[0], hw[1], hw[2], hw[3]);
        hb[1] = make_uint4(hw[4], hw[5], hw[6], hw[7]);
        hb[2] = make_uint4(hw[8], hw[9], hw[10], hw[11]);
        hb[3] = make_uint4(hw[12], hw[13], hw[14], hw[15]);

        const float* xp = x1 + (size_t)src[eid] * C1;
        uint4* xb = (uint4*)&s_x1b[t * 40];
        #pragma unroll
        for (int q = 0; q < 4; ++q) {
            const float4 v0 = *(const float4*)(xp + q * 8);
            const float4 v1 = *(const float4*)(xp + q * 8 + 4);
            xb[q] = make_uint4(pack2(v0.x, v0.y), pack2(v0.z, v0.w),
                               pack2(v1.x, v1.y), pack2(v1.z, v1.w));
        }
    }
    __syncthreads();

    const int wv = t >> 6, lane = t & 63;
    const int n = lane & 15, quad = lane >> 4;
    const int e0 = wv * 64;

    float xf[4][8];
    #pragma unroll
    for (int m = 0; m < 4; ++m) {
        const uint4 xv = *(const uint4*)&s_x1b[(e0 + m * 16 + n) * 40 + quad * 8];
        xf[m][0] = __uint_as_float(xv.x << 16);
        xf[m][1] = __uint_as_float(xv.x & 0xFFFF0000u);
        xf[m][2] = __uint_as_float(xv.y << 16);
        xf[m][3] = __uint_as_float(xv.y & 0xFFFF0000u);
        xf[m][4] = __uint_as_float(xv.z << 16);
        xf[m][5] = __uint_as_float(xv.z & 0xFFFF0000u);
        xf[m][6] = __uint_as_float(xv.w << 16);
        xf[m][7] = __uint_as_float(xv.w & 0xFFFF0000u);
    }

    f32x4 acc[4][4];
    #pragma unroll
    for (int m = 0; m < 4; ++m)
        #pragma unroll
        for (int nt = 0; nt < 4; ++nt) acc[m][nt] = (f32x4){0.f, 0.f, 0.f, 0.f};

    #pragma unroll 4
    for (int kc = 0; kc < 32; ++kc) {
        bf16x8 bfr[4];
        #pragma unroll
        for (int nt = 0; nt < 4; ++nt)
            bfr[nt] = *(const bf16x8*)(wbt2 + (((kc * 4 + nt) * 16 + n) << 5) + quad * 8);
        #pragma unroll
        for (int m = 0; m < 4; ++m) {
            const unsigned hv = s_h1b[(e0 + m * 16 + n) * 40 + kc];
            const float hf = __uint_as_float(hv << 16);
            union { unsigned u[4]; bf16x8 v; } af;
            #pragma unroll
            for (int i = 0; i < 4; ++i)
                af.u[i] = pack2(hf * xf[m][2 * i], hf * xf[m][2 * i + 1]);
            #pragma unroll
            for (int nt = 0; nt < 4; ++nt)
                acc[m][nt] = __builtin_amdgcn_mfma_f32_16x16x32_bf16(af.v, bfr[nt], acc[m][nt], 0, 0, 0);
        }
    }

    #pragma unroll
    for (int m = 0; m < 4; ++m)
        #pragma unroll
        for (int r = 0; r < 4; ++r) {
            const int p = s_perm[e0 + m * 16 + quad * 4 + r];
            uint2 val;
            val.x = pack2(acc[m][0][r], acc[m][1][r]);
            val.y = pack2(acc[m][2][r], acc[m][3][r]);
            *(uint2*)&msg2[p * 32 + n * 2] = val;
        }
}

// gather msg2 (sequential) + node update 2 + xw = x2 @ gcn_W -> xw
__global__ __launch_bounds__(256) void gather2(
    const unsigned* __restrict__ msg2, const int* __restrict__ off,
    const float* __restrict__ x1,
    const float* __restrict__ root, const float* __restrict__ bias,
    const float* __restrict__ W, float* __restrict__ xw)
{
    __shared__ float s_root[2048], s_W[2048], s_b[64];
    __shared__ float s_x2[8][68];
    __shared__ float s_x1v[256];
    const int t = threadIdx.x;
    for (int i = t; i < 2048; i += 256) { s_root[i] = root[i]; s_W[i] = W[i]; }
    if (t < 64) s_b[t] = bias[t];
    s_x1v[t] = x1[blockIdx.x * 256 + t];
    __syncthreads();

    const int lv = t >> 5;
    const int v = blockIdx.x * 8 + lv;
    const int j5 = t & 31;
    const int n = j5 >> 1, p = j5 & 1;
    const int ca = p * 32 + n, cb = p * 32 + 16 + n;
    const int o0 = off[v], o1 = off[v + 1];
    float sa = 0.f, sb = 0.f;
    for (int j = o0; j < o1; ++j) {
        const unsigned u = msg2[j * 32 + j5];
        sa += __uint_as_float(u << 16);
        sb += __uint_as_float(u & 0xFFFF0000u);
    }
    float ra = s_b[ca], rb = s_b[cb];
    #pragma unroll 8
    for (int k = 0; k < 32; ++k) {
        const float xv = s_x1v[lv * 32 + k];
        ra += xv * s_root[k * 64 + ca];
        rb += xv * s_root[k * 64 + cb];
    }
    s_x2[lv][ca] = fmaxf(sa + ra, 0.f);
    s_x2[lv][cb] = fmaxf(sb + rb, 0.f);
    __syncthreads();

    float av = 0.f;
    #pragma unroll 8
    for (int k = 0; k < 64; ++k) av += s_x2[lv][k] * s_W[k * 32 + j5];
    xw[v * 32 + j5] = av;
}

// GCN gather (CSR-ordered srcp/gwp, sequential) + relu + global pool
__global__ __launch_bounds__(256) void gcn_pool(
    const float* __restrict__ xw, const int* __restrict__ off,
    const int* __restrict__ srcp, const float* __restrict__ gwp,
    const float* __restrict__ gw, const float* __restrict__ gb,
    const int* __restrict__ seg, float* __restrict__ out)
{
    __shared__ float s_gb[32];
    const int t = threadIdx.x;
    if (t < 32) s_gb[t] = gb[t];
    __syncthreads();
    const int v = blockIdx.x * 8 + (t >> 5);
    const int c = t & 31;
    const int o0 = off[v], o1 = off[v + 1];
    float s = gw[E_EDGES + v] * xw[v * 32 + c];   // self loop
    for (int j = o0; j < o1; ++j)
        s += gwp[j] * xw[srcp[j] * 32 + c];
    const float val = fmaxf(s + s_gb[c], 0.f);
    atomicAdd(&out[seg[v] * 32 + c], val);
}

extern "C" void kernel_launch(void* const* d_in, const int* in_sizes, int n_in,
                              void* d_out, int out_size, void* d_ws, size_t ws_size,
                              hipStream_t stream)
{
    const float* x       = (const float*)d_in[0];
    const float* e       = (const float*)d_in[1];
    const int*   src     = (const int*)d_in[2];
    const int*   tgt     = (const int*)d_in[3];
    const int*   seg     = (const int*)d_in[4];
    const float* gcn_w   = (const float*)d_in[7];
    const float* e1_w0   = (const float*)d_in[8];
    const float* e1_b0   = (const float*)d_in[9];
    const float* e1_w1   = (const float*)d_in[10];
    const float* e1_b1   = (const float*)d_in[11];
    const float* e1_wk   = (const float*)d_in[12];
    const float* e1_bk   = (const float*)d_in[13];
    const float* e1_root = (const float*)d_in[14];
    const float* e1_bias = (const float*)d_in[15];
    const float* e2_w0   = (const float*)d_in[16];
    const float* e2_b0   = (const float*)d_in[17];
    const float* e2_w1   = (const float*)d_in[18];
    const float* e2_b1   = (const float*)d_in[19];
    const float* e2_wk   = (const float*)d_in[20];
    const float* e2_bk   = (const float*)d_in[21];
    const float* e2_root = (const float*)d_in[22];
    const float* e2_bias = (const float*)d_in[23];
    const float* gcn_W   = (const float*)d_in[24];
    const float* gcn_b   = (const float*)d_in[25];
    float* out = (float*)d_out;

    float*    ws    = (float*)d_ws;
    float*    x1    = ws;                                   // [N,32]
    float*    xw    = x1 + (size_t)N_NODES * 32;            // [N,32]
    unsigned* msg1  = (unsigned*)(xw + (size_t)N_NODES * 32);   // E*16 u32
    unsigned* msg2  = msg1 + (size_t)E_EDGES * 16;          // E*32 u32
    short*    wbt2  = (short*)(msg2 + (size_t)E_EDGES * 32);// 65536 bf16
    short*    wbt1  = wbt2 + 65536;                         // 8192 bf16
    int*      deg   = (int*)(wbt1 + 8192);                  // N
    int*      off   = deg + N_NODES;                        // N+1 (+pad)
    int*      cursor= off + N_NODES + 16;                   // N
    int*      perm  = cursor + N_NODES;                     // E
    int*      srcp  = perm + E_EDGES;                       // E
    float*    gwp   = (float*)(srcp + E_EDGES);             // E

    hipMemsetAsync(deg, 0, N_NODES * sizeof(int), stream);
    hipMemsetAsync(out, 0, (size_t)out_size * sizeof(float), stream);

    prep<<<E_EDGES / 256, 256, 0, stream>>>(e2_wk, e2_bk, e1_wk, e1_bk, tgt,
        wbt2, wbt1, deg);
    csr_scan<<<1, 1024, 0, stream>>>(deg, off, cursor);

    ecc1_mfma<<<E_EDGES / 256, 256, 0, stream>>>(x, e, src, tgt, gcn_w,
        e1_w0, e1_b0, e1_w1, e1_b1, wbt1, cursor, perm, srcp, gwp, msg1);
    gather1<<<N_NODES / 16, 256, 0, stream>>>(msg1, off, x, e1_root, e1_bias, x1);
    ecc2_mfma<<<E_EDGES / 256, 256, 0, stream>>>(x1, e, src, perm,
        e2_w0, e2_b0, e2_w1, e2_b1, wbt2, msg2);
    gather2<<<N_NODES / 8, 256, 0, stream>>>(msg2, off, x1,
        e2_root, e2_bias, gcn_W, xw);
    gcn_pool<<<N_NODES / 8, 256, 0, stream>>>(xw, off, srcp, gwp,
        gcn_w, gcn_b, seg, out);
}